// Round 2
// baseline (233.565 us; speedup 1.0000x reference)
//
#include <hip/hip_runtime.h>
#include <math.h>

#define B_ 8
#define T_ 1024
#define C_ 768
#define H_ 8
#define D_ 96
#define M_ (B_ * T_)     // 8192 tokens
#define N1_ (3 * C_)     // 2304
#define KD_ 768          // K of both GEMMs

typedef __bf16 bf16x8 __attribute__((ext_vector_type(8)));
typedef float f32x4 __attribute__((ext_vector_type(4)));
typedef float f32x16 __attribute__((ext_vector_type(16)));

__device__ __forceinline__ unsigned short f2bf(float f) {
  unsigned int u = __float_as_uint(f);
  u += 0x7FFF + ((u >> 16) & 1);          // round-to-nearest-even
  return (unsigned short)(u >> 16);
}

// async global->LDS, 16B per lane; LDS dest = uniform base + lane*16
__device__ __forceinline__ void load_lds16(const void* g, void* l) {
  __builtin_amdgcn_global_load_lds(
      (const __attribute__((address_space(1))) unsigned int*)g,
      (__attribute__((address_space(3))) unsigned int*)l, 16, 0, 0);
}

// ---------------------------------------------------------------------------
// Fused prep: blocks 0..6143 cast x to bf16 (1024 elems each);
// blocks 6144.. transpose W_attn / W_proj to [N][K] bf16.
// ---------------------------------------------------------------------------
__global__ __launch_bounds__(256) void prep_kernel(
    const float* __restrict__ x, unsigned short* __restrict__ xb,
    const float* __restrict__ Wa, unsigned short* __restrict__ WaT,
    const float* __restrict__ Wp, unsigned short* __restrict__ WpT) {
  __shared__ float Lt[32][33];
  int bid = blockIdx.x;
  if (bid < 6144) {
    int i = (bid * 256 + threadIdx.x) * 4;
    float4 v = *(const float4*)(x + i);
    ushort4 o;
    o.x = f2bf(v.x); o.y = f2bf(v.y); o.z = f2bf(v.z); o.w = f2bf(v.w);
    *(ushort4*)(xb + i) = o;
    return;
  }
  bid -= 6144;
  const float* W; unsigned short* WT; int Nd;
  if (bid < 1728) { W = Wa; WT = WaT; Nd = N1_; }
  else            { W = Wp; WT = WpT; Nd = C_; bid -= 1728; }
  const int r0 = (bid % 24) * 32;   // Kd
  const int c0 = (bid / 24) * 32;   // Nd
#pragma unroll
  for (int i = 0; i < 4; ++i) {
    int e = threadIdx.x + 256 * i;
    int r = e >> 5, c = e & 31;
    Lt[r][c] = W[(size_t)(r0 + r) * Nd + c0 + c];
  }
  __syncthreads();
#pragma unroll
  for (int i = 0; i < 4; ++i) {
    int e = threadIdx.x + 256 * i;
    int rr = e >> 5, cc = e & 31;
    WT[(size_t)(c0 + rr) * KD_ + r0 + cc] = f2bf(Lt[cc][rr]);
  }
}

// ---------------------------------------------------------------------------
// R10: 256x256-tile QKV GEMM (m201-regime structure, plain HIP).
// Diagnosis: the 128x128 kernel ran at 414 TF == 64 FLOP/staged-byte x
// 6.4 TB/s load-path -> staging-intensity-bound; pipelining tweaks were null.
// Fix: double intensity (128 FLOP/byte) + the deep-pipeline 8-wave schedule.
//  - 512 thr = 8 waves (2M x 4N); per-wave 128x64 out = 4x2 acc of 32x32
//    (128 AGPR; launch_bounds(512,2) caps at 256 VGPR -> 2 waves/SIMD).
//  - BK=32; LDS = 4 buffers x 32KB (A 8 chunks x2kh + B 8x2, 1KB lane-order
//    chunks: lane l <-> [row=l&31][k=(l>>5)*8..+7] -> 0 bank conflicts).
//  - Stage 3 tiles ahead (12 gload_lds/wave in flight); per K-step:
//    counted s_waitcnt vmcnt(8) [tail 4/0] + ONE s_barrier; stage(t+3)
//    right after barrier. Safety: before bar(t) every wave waited for its
//    own tile-t chunks; bar(t) also proves all waves finished compute(t-1),
//    and stage target (t+3)&3 == (t-1)&3.
//  - s_setprio(1) around each 8-MFMA cluster (T5; phase-split schedule).
//  - Grid 288 = 32m x 9n; bijective XCD chunk swizzle (288 = 8*36).
// Epilogue: bias + q-scale (col<768); V cols (>=1536) scatter to vt[bh][d][t].
// C/D frag: col = lane&31, row = (r&3)+8*(r>>2)+4*(lane>>5)  [m74/m101].
// ---------------------------------------------------------------------------
__global__ __launch_bounds__(512, 2) void gemm256_kernel(
    const unsigned short* __restrict__ A, const unsigned short* __restrict__ Bt,
    const float* __restrict__ bias, unsigned short* __restrict__ Cout,
    unsigned short* __restrict__ vt, float sc) {
  __shared__ __align__(16) unsigned short Sb[4][32 * 512];  // 128 KB
  const int tid = threadIdx.x;
  const int w = tid >> 6, l = tid & 63;
  const int l31 = l & 31, lh = l >> 5;
  const int wm = w >> 2, wn = w & 3;

  const int bid = blockIdx.x;
  const int swz = (bid & 7) * 36 + (bid >> 3);   // XCD-chunked, bijective
  const int m0 = (swz & 31) * 256, n0 = (swz >> 5) * 256;

  f32x16 acc[4][2];
#pragma unroll
  for (int mi = 0; mi < 4; ++mi)
#pragma unroll
    for (int ni = 0; ni < 2; ++ni)
#pragma unroll
      for (int r = 0; r < 16; ++r) acc[mi][ni][r] = 0.f;

  // 32 chunks/buffer, 4 per wave. c<16: A chunk (pr=c>>1, kh=c&1);
  // c>=16: B chunk (pn=(c>>1)&7, kh=c&1).
  const unsigned short* gp[4];
#pragma unroll
  for (int i = 0; i < 4; ++i) {
    const int c = w * 4 + i;
    const int kh = c & 1, pr = (c >> 1) & 7;
    gp[i] = (c < 16)
        ? A  + (size_t)(m0 + pr * 32 + l31) * KD_ + kh * 16 + lh * 8
        : Bt + (size_t)(n0 + pr * 32 + l31) * KD_ + kh * 16 + lh * 8;
  }

  auto stage = [&](int buf) {
#pragma unroll
    for (int i = 0; i < 4; ++i) {
      load_lds16(gp[i], &Sb[buf][(w * 4 + i) * 512]);
      gp[i] += 32;
    }
  };

  // prologue: tiles 0,1,2 -> buffers 0,1,2 (12 loads/wave outstanding)
  stage(0); stage(1); stage(2);

  for (int t = 0; t < 24; ++t) {
    const int ahead = 23 - t;
    if (ahead >= 2)      asm volatile("s_waitcnt vmcnt(8)" ::: "memory");
    else if (ahead == 1) asm volatile("s_waitcnt vmcnt(4)" ::: "memory");
    else                 asm volatile("s_waitcnt vmcnt(0)" ::: "memory");
    __builtin_amdgcn_s_barrier();
    asm volatile("" ::: "memory");  // pin: no LDS access crosses the barrier

    if (t + 3 < 24) stage((t + 3) & 3);

    const int cb = t & 3;
#pragma unroll
    for (int kh = 0; kh < 2; ++kh) {
      bf16x8 af[4], bfr[2];
#pragma unroll
      for (int mi = 0; mi < 4; ++mi)
        af[mi] = *(const bf16x8*)&Sb[cb][((wm * 4 + mi) * 2 + kh) * 512 + l * 8];
#pragma unroll
      for (int ni = 0; ni < 2; ++ni)
        bfr[ni] = *(const bf16x8*)&Sb[cb][(16 + (wn * 2 + ni) * 2 + kh) * 512 + l * 8];
      __builtin_amdgcn_s_setprio(1);
#pragma unroll
      for (int mi = 0; mi < 4; ++mi)
#pragma unroll
        for (int ni = 0; ni < 2; ++ni)
          acc[mi][ni] = __builtin_amdgcn_mfma_f32_32x32x16_bf16(
              af[mi], bfr[ni], acc[mi][ni], 0, 0, 0);
      __builtin_amdgcn_s_setprio(0);
    }
  }

#pragma unroll
  for (int mi = 0; mi < 4; ++mi) {
    const int rowb = m0 + wm * 128 + mi * 32 + 4 * lh;
#pragma unroll
    for (int ni = 0; ni < 2; ++ni) {
      const int col = n0 + wn * 64 + ni * 32 + l31;
      const float bv = bias[col];
      if (col < 1536) {
        const float mul = (col < C_) ? sc : 1.f;
#pragma unroll
        for (int r = 0; r < 16; ++r) {
          const int row = rowb + (r & 3) + 8 * (r >> 2);
          Cout[(size_t)row * N1_ + col] = f2bf((acc[mi][ni][r] + bv) * mul);
        }
      } else {
        const int x = col - 1536;
        const int h = x / 96, d = x % 96;
#pragma unroll
        for (int r = 0; r < 16; ++r) {
          const int row = rowb + (r & 3) + 8 * (r >> 2);
          const int bb = row >> 10, t = row & 1023;
          vt[((size_t)(bb * H_ + h) * D_ + d) * T_ + t] =
              f2bf(acc[mi][ni][r] + bv);
        }
      }
    }
  }
}

// ---------------------------------------------------------------------------
// bf16 MFMA GEMM (R9 structure) — retained for the proj GEMM only.
// 3-buffer / 2-ahead pipeline with counted vmcnt + raw s_barrier.
// ---------------------------------------------------------------------------
template <int WM32, bool OUTF32, bool VSCAT>
__global__ __launch_bounds__(256, WM32 == 2 ? 3 : 4) void gemm_mfma_kernel(
    const unsigned short* __restrict__ A, const unsigned short* __restrict__ Bt,
    const float* __restrict__ bias, void* __restrict__ Cout,
    unsigned short* __restrict__ vt, int N,
    int sc_lim, float sc, int mmask, int mshift) {
  constexpr int AS2 = 2 * WM32;        // A 32-row blocks per tile
  constexpr int NCH = AS2 * 2 + 8;     // 1KB chunks per buffer
  constexpr int CPW = NCH / 4;         // chunks staged per wave
  __shared__ __align__(16) unsigned short Sb[3][NCH * 512];
  const int tid = threadIdx.x;
  const int w = tid >> 6, l = tid & 63;
  const int l31 = l & 31, lh = l >> 5;
  const int bid = blockIdx.x;
  const int m0 = (bid & mmask) * (AS2 * 32), n0 = (bid >> mshift) * 128;
  const int wrb = (w >> 1) * WM32;     // wave A-block base
  const int wnb = (w & 1) * 2;         // wave B-block base

  f32x16 acc[WM32][2];
#pragma unroll
  for (int i = 0; i < WM32; ++i)
#pragma unroll
    for (int j = 0; j < 2; ++j)
#pragma unroll
      for (int r = 0; r < 16; ++r) acc[i][j][r] = 0.f;

  const unsigned short* gp[CPW];
#pragma unroll
  for (int i = 0; i < CPW; ++i) {
    const int c = w * CPW + i;
    const int pr = c >> 1, kh = c & 1;
    gp[i] = (pr < AS2)
        ? A  + (size_t)(m0 + pr * 32 + l31) * KD_ + kh * 16 + lh * 8
        : Bt + (size_t)(n0 + (pr - AS2) * 32 + l31) * KD_ + kh * 16 + lh * 8;
  }

  // prologue: stage tiles 0 and 1 into buffers 0,1
#pragma unroll
  for (int t = 0; t < 2; ++t)
#pragma unroll
    for (int i = 0; i < CPW; ++i) {
      load_lds16(gp[i], &Sb[t][(w * CPW + i) * 512]);
      gp[i] += 32;
    }

  int cur = 0, stg = 2;
  for (int k0 = 0; k0 < KD_; k0 += 32) {
    if (k0 + 32 < KD_) {
      if constexpr (CPW == 4) asm volatile("s_waitcnt vmcnt(4)" ::: "memory");
      else                    asm volatile("s_waitcnt vmcnt(3)" ::: "memory");
    } else {
      asm volatile("s_waitcnt vmcnt(0)" ::: "memory");
    }
    __builtin_amdgcn_s_barrier();
    asm volatile("" ::: "memory");  // pin: no mem op crosses the barrier

    if (k0 + 64 < KD_) {
#pragma unroll
      for (int i = 0; i < CPW; ++i) {
        load_lds16(gp[i], &Sb[stg][(w * CPW + i) * 512]);
        gp[i] += 32;
      }
    }

#pragma unroll
    for (int kh = 0; kh < 2; ++kh) {
      bf16x8 af[WM32], bfr[2];
#pragma unroll
      for (int mi = 0; mi < WM32; ++mi)
        af[mi] = *(const bf16x8*)&Sb[cur][((wrb + mi) * 2 + kh) * 512 + l * 8];
#pragma unroll
      for (int ni = 0; ni < 2; ++ni)
        bfr[ni] = *(const bf16x8*)&Sb[cur][((AS2 + wnb + ni) * 2 + kh) * 512 + l * 8];
#pragma unroll
      for (int mi = 0; mi < WM32; ++mi)
#pragma unroll
        for (int ni = 0; ni < 2; ++ni)
          acc[mi][ni] = __builtin_amdgcn_mfma_f32_32x32x16_bf16(
              af[mi], bfr[ni], acc[mi][ni], 0, 0, 0);
    }
    cur = (cur == 2) ? 0 : cur + 1;
    stg = (stg == 2) ? 0 : stg + 1;
  }

  const bool vblock = VSCAT && (n0 >= 1536);
#pragma unroll
  for (int mi = 0; mi < WM32; ++mi) {
    const int rowb = m0 + (wrb + mi) * 32 + 4 * lh;
#pragma unroll
    for (int ni = 0; ni < 2; ++ni) {
      const int col = n0 + (wnb + ni) * 32 + l31;
      const float bv = bias[col];
      if (!vblock) {
        const float mul = (col < sc_lim) ? sc : 1.f;
#pragma unroll
        for (int r = 0; r < 16; ++r) {
          const int row = rowb + (r & 3) + 8 * (r >> 2);
          float v = (acc[mi][ni][r] + bv) * mul;
          if (OUTF32)
            ((float*)Cout)[(size_t)row * N + col] = v;
          else
            ((unsigned short*)Cout)[(size_t)row * N + col] = f2bf(v);
        }
      } else {
        const int x = col - 1536;
        const int h = x / 96, d = x % 96;
#pragma unroll
        for (int r = 0; r < 16; ++r) {
          const int row = rowb + (r & 3) + 8 * (r >> 2);
          const int bb = row >> 10, t = row & 1023;
          vt[((size_t)(bb * H_ + h) * D_ + d) * T_ + t] =
              f2bf(acc[mi][ni][r] + bv);
        }
      }
    }
  }
}

// ---------------------------------------------------------------------------
// Flash causal attention (unchanged): bf16 MFMA 16x16x32, max-free softmax
// (Q pre-scaled), l via ones-MFMA, paired q-tiles (17 key-tiles/block),
// K/V double-buffered LDS, XCD swizzle bh = id & 63.
// ---------------------------------------------------------------------------
__global__ __launch_bounds__(256) void attn_mfma_kernel(
    const unsigned short* __restrict__ qkv,  // [8192][2304], Q pre-scaled
    const unsigned short* __restrict__ vt,   // [64][96][1024]
    unsigned short* __restrict__ y) {        // [8192][768]
  __shared__ __align__(16) unsigned short KV[2][24 * 512];  // 48 KB
  __shared__ __align__(16) unsigned short Pt[4][16][72];    // pad 64->72

  const int tid = threadIdx.x;
  const int w = tid >> 6, l = tid & 63;
  const int lm = l & 15, lq = l >> 4;
  const int bh = blockIdx.x & 63, pi = blockIdx.x >> 6;
  const int b = bh >> 3, h = bh & 7;
  const size_t bT = (size_t)b * T_;

  bf16x8 onef;
#pragma unroll
  for (int i = 0; i < 8; ++i) onef[i] = (__bf16)1.0f;

  auto issue = [&](int j0, int buf) {
#pragma unroll
    for (int i = 0; i < 6; ++i) {
      const int c = w * 6 + i;
      const unsigned short* g;
      if (c < 12) {
        const int kc = c >> 2, nb = c & 3;
        g = qkv + (bT + j0 + nb * 16 + lm) * N1_ + C_ + h * D_ + kc * 32 + lq * 8;
      } else {
        const int cv = c - 12;
        const int db = cv >> 1, vc = cv & 1;
        g = vt + ((size_t)bh * D_ + db * 16 + lm) * T_ + j0 + vc * 32 + lq * 8;
      }
      load_lds16(g, &KV[buf][c * 512]);
    }
  };

  int cur = 0;
  issue(0, 0);

  for (int half = 0; half < 2; ++half) {
    const int qt = half ? (15 - pi) : pi;
    const int q0 = qt * 64;

    bf16x8 qf[3];
    {
      const unsigned short* qp =
          qkv + (bT + q0 + w * 16 + lm) * N1_ + h * D_ + lq * 8;
      qf[0] = *(const bf16x8*)(qp);
      qf[1] = *(const bf16x8*)(qp + 32);
      qf[2] = *(const bf16x8*)(qp + 64);
    }
    f32x4 o[7];
#pragma unroll
    for (int i = 0; i < 7; ++i) o[i] = (f32x4){0.f, 0.f, 0.f, 0.f};

    for (int jt = 0; jt <= qt; ++jt) {
      __syncthreads();
      if (jt < qt)          issue((jt + 1) * 64, cur ^ 1);
      else if (half == 0)   issue(0, cur ^ 1);

      const bool diag = (jt == qt);
#pragma unroll
      for (int nb = 0; nb < 4; ++nb) {
        if (diag && nb > w) {
#pragma unroll
          for (int r = 0; r < 4; ++r)
            Pt[w][lq * 4 + r][nb * 16 + lm] = 0;
          continue;
        }
        f32x4 a = (f32x4){0.f, 0.f, 0.f, 0.f};
#pragma unroll
        for (int kc = 0; kc < 3; ++kc) {
          bf16x8 kf = *(const bf16x8*)&KV[cur][(kc * 4 + nb) * 512 + l * 8];
          a = __builtin_amdgcn_mfma_f32_16x16x32_bf16(qf[kc], kf, a, 0, 0, 0);
        }
#pragma unroll
        for (int r = 0; r < 4; ++r) {
          float s = a[r];
          if (diag && (nb * 16 + lm > w * 16 + lq * 4 + r)) s = -INFINITY;
          Pt[w][lq * 4 + r][nb * 16 + lm] = f2bf(__expf(s));
        }
      }

      bf16x8 pf0 = *(const bf16x8*)&Pt[w][lm][lq * 8];
      bf16x8 pf1 = *(const bf16x8*)&Pt[w][lm][32 + lq * 8];
#pragma unroll
      for (int db = 0; db < 6; ++db) {
        bf16x8 vf0 = *(const bf16x8*)&KV[cur][(12 + db * 2 + 0) * 512 + l * 8];
        bf16x8 vf1 = *(const bf16x8*)&KV[cur][(12 + db * 2 + 1) * 512 + l * 8];
        o[db] = __builtin_amdgcn_mfma_f32_16x16x32_bf16(pf0, vf0, o[db], 0, 0, 0);
        o[db] = __builtin_amdgcn_mfma_f32_16x16x32_bf16(pf1, vf1, o[db], 0, 0, 0);
      }
      o[6] = __builtin_amdgcn_mfma_f32_16x16x32_bf16(pf0, onef, o[6], 0, 0, 0);
      o[6] = __builtin_amdgcn_mfma_f32_16x16x32_bf16(pf1, onef, o[6], 0, 0, 0);
      cur ^= 1;
    }

#pragma unroll
    for (int r = 0; r < 4; ++r) {
      const float inv = 1.f / o[6][r];
      const size_t row = bT + q0 + w * 16 + lq * 4 + r;
#pragma unroll
      for (int db = 0; db < 6; ++db)
        y[row * C_ + h * D_ + db * 16 + lm] = f2bf(o[db][r] * inv);
    }
  }
}

// ---------------------------------------------------------------------------
extern "C" void kernel_launch(void* const* d_in, const int* in_sizes, int n_in,
                              void* d_out, int out_size, void* d_ws, size_t ws_size,
                              hipStream_t stream) {
  const float* x      = (const float*)d_in[0];
  const float* W_attn = (const float*)d_in[1];
  const float* b_attn = (const float*)d_in[2];
  const float* W_proj = (const float*)d_in[3];
  const float* b_proj = (const float*)d_in[4];
  float* out = (float*)d_out;

  char* ws = (char*)d_ws;
  unsigned short* xb  = (unsigned short*)(ws);                    // 12.58 MB
  unsigned short* WaT = (unsigned short*)(ws + 12582912);         //  3.54 MB
  unsigned short* WpT = (unsigned short*)(ws + 16121856);         //  1.18 MB
  unsigned short* qkv = (unsigned short*)(ws + 17301504);         // 37.75 MB
  unsigned short* vt  = (unsigned short*)(ws + 55050240);         // 12.58 MB
  unsigned short* yb  = (unsigned short*)(ws + 67633152);         // 12.58 MB

  const float qscale = 0.10206207261596577f;  // 1/sqrt(96)

  // fused prep: x cast (6144 blocks) + both W transposes (2304 blocks)
  prep_kernel<<<6144 + 2304, 256, 0, stream>>>(x, xb, W_attn, WaT, W_proj, WpT);

  // qkv = x @ W_attn + b_attn: 256x256 tiles, 288 blocks, 512 threads
  gemm256_kernel<<<(M_ / 256) * (N1_ / 256), 512, 0, stream>>>(
      xb, WaT, b_attn, qkv, vt, qscale);
  // attn: 512 blocks, bh = id & 63 for XCD locality
  attn_mfma_kernel<<<8 * B_ * H_, 256, 0, stream>>>(qkv, vt, yb);
  // proj: 64x128 tiles, 128 m-panels
  gemm_mfma_kernel<1, true, false><<<(C_ / 128) * (M_ / 64), 256, 0, stream>>>(
      yb, WpT, b_proj, out, nullptr, C_, 0, 1.f, 127, 7);
}

// Round 3
// 224.453 us; speedup vs baseline: 1.0406x; 1.0406x over previous
//
#include <hip/hip_runtime.h>
#include <math.h>

#define B_ 8
#define T_ 1024
#define C_ 768
#define H_ 8
#define D_ 96
#define M_ (B_ * T_)     // 8192 tokens
#define N1_ (3 * C_)     // 2304
#define KD_ 768          // K of both GEMMs

typedef __bf16 bf16x8 __attribute__((ext_vector_type(8)));
typedef float f32x4 __attribute__((ext_vector_type(4)));
typedef float f32x16 __attribute__((ext_vector_type(16)));

__device__ __forceinline__ unsigned short f2bf(float f) {
  unsigned int u = __float_as_uint(f);
  u += 0x7FFF + ((u >> 16) & 1);          // round-to-nearest-even
  return (unsigned short)(u >> 16);
}

// async global->LDS, 16B per lane; LDS dest = uniform base + lane*16
__device__ __forceinline__ void load_lds16(const void* g, void* l) {
  __builtin_amdgcn_global_load_lds(
      (const __attribute__((address_space(1))) unsigned int*)g,
      (__attribute__((address_space(3))) unsigned int*)l, 16, 0, 0);
}

// ---------------------------------------------------------------------------
// Fused prep: blocks 0..6143 cast x to bf16 (1024 elems each);
// blocks 6144.. transpose W_attn / W_proj to [N][K] bf16.
// ---------------------------------------------------------------------------
__global__ __launch_bounds__(256) void prep_kernel(
    const float* __restrict__ x, unsigned short* __restrict__ xb,
    const float* __restrict__ Wa, unsigned short* __restrict__ WaT,
    const float* __restrict__ Wp, unsigned short* __restrict__ WpT) {
  __shared__ float Lt[32][33];
  int bid = blockIdx.x;
  if (bid < 6144) {
    int i = (bid * 256 + threadIdx.x) * 4;
    float4 v = *(const float4*)(x + i);
    ushort4 o;
    o.x = f2bf(v.x); o.y = f2bf(v.y); o.z = f2bf(v.z); o.w = f2bf(v.w);
    *(ushort4*)(xb + i) = o;
    return;
  }
  bid -= 6144;
  const float* W; unsigned short* WT; int Nd;
  if (bid < 1728) { W = Wa; WT = WaT; Nd = N1_; }
  else            { W = Wp; WT = WpT; Nd = C_; bid -= 1728; }
  const int r0 = (bid % 24) * 32;   // Kd
  const int c0 = (bid / 24) * 32;   // Nd
#pragma unroll
  for (int i = 0; i < 4; ++i) {
    int e = threadIdx.x + 256 * i;
    int r = e >> 5, c = e & 31;
    Lt[r][c] = W[(size_t)(r0 + r) * Nd + c0 + c];
  }
  __syncthreads();
#pragma unroll
  for (int i = 0; i < 4; ++i) {
    int e = threadIdx.x + 256 * i;
    int rr = e >> 5, cc = e & 31;
    WT[(size_t)(c0 + rr) * KD_ + r0 + cc] = f2bf(Lt[cc][rr]);
  }
}

// ---------------------------------------------------------------------------
// R11: 256x256 QKV GEMM with the TRUE 8-phase m201 schedule (T3+T4+T5).
// R10 post-mortem: one-barrier-per-BK32 coarse schedule at 1 blk/CU =
// T_blk 44.5us (2.7x off m201 rate) + 288-on-256 tail (2x) + XCD swizzle
// spanning all m-panels (FETCH 2x). Fixes:
//  - BK=64, 2 K-tiles/iteration, 8 phases/iteration. Per phase:
//    {6x ds_read_b128 frags; stage one 16KB quarter-unit (2 gload_lds/wave);
//     barrier; setprio(1); 8x mfma_32x32x16; setprio(0); [vmcnt at p3/p7]
//     barrier}. Fine ds_read || stage || MFMA interleave = m196's lever.
//  - Unit stream: unit g = (tile g>>2, kh g&3), 16 chunks = 2 loads/wave;
//    stage at phase p issues g = 8*it+7+p (prologue g=0..6, 14 loads/wave
//    in flight). Counted vmcnt(6) at END of p3 (gates tile 2it+1) and p7
//    (gates tile 2it+2), BEFORE the trailing barrier so every wave's
//    quarter-units are visible to all waves after it. Last iter: vmcnt(0)
//    at p3, none at p7. Never drains mid-loop otherwise (T4).
//  - WAR safety: stage at phase p overwrites the kh-chunk last read at
//    phase p-1, whose reads completed before p-1's trailing barrier.
//  - LDS: 2 bufs x 64KB (64 lane-linear 1KB chunks: A pr*4+kh, B 32+pn*4+kh)
//    -> conflict-free ds_read_b128 (proven 0 conflicts).
//  - XCD swizzle: xcd=bid&7 owns a 4m x 9n chunk (A set 1.57MB < 4MB L2).
// Epilogue: bias + q-scale (col<768); V cols (>=1536) scatter to vt[bh][d][t].
// C/D frag: col = lane&31, row = (r&3)+8*(r>>2)+4*(lane>>5)  [m74/m101].
// ---------------------------------------------------------------------------
__global__ __launch_bounds__(512, 2) void gemm256_kernel(
    const unsigned short* __restrict__ A, const unsigned short* __restrict__ Bt,
    const float* __restrict__ bias, unsigned short* __restrict__ Cout,
    unsigned short* __restrict__ vt, float sc) {
  __shared__ __align__(16) unsigned short Sb[2][64 * 512];  // 2 x 64 KB
  const int tid = threadIdx.x;
  const int w = tid >> 6, l = tid & 63;
  const int l31 = l & 31, lh = l >> 5;
  const int wm = w >> 2, wn = w & 3;

  const int bid = blockIdx.x;
  const int xcd = bid & 7, j = bid >> 3;         // 8 XCDs x 36 tiles
  const int m0 = (xcd * 4 + (j & 3)) * 256;      // 4 m-panels per XCD
  const int n0 = (j >> 2) * 256;                 // 9 n-panels

  f32x16 acc[4][2];
#pragma unroll
  for (int mi = 0; mi < 4; ++mi)
#pragma unroll
    for (int ni = 0; ni < 2; ++ni)
#pragma unroll
      for (int r = 0; r < 16; ++r) acc[mi][ni][r] = 0.f;

  // per-wave staging: 2 chunks per quarter-unit. u = w*2+i: u<8 -> A pr=u,
  // u>=8 -> B pn=u-8. Column advance per unit g: tile(g>>2)*64+(g&3)*16 = g*16.
  const unsigned short* gbase[2];
  int cb_[2];
#pragma unroll
  for (int i = 0; i < 2; ++i) {
    const int u = w * 2 + i;
    if (u < 8) {
      gbase[i] = A + (size_t)(m0 + u * 32 + l31) * KD_ + lh * 8;
      cb_[i] = u * 4;
    } else {
      gbase[i] = Bt + (size_t)(n0 + (u - 8) * 32 + l31) * KD_ + lh * 8;
      cb_[i] = 32 + (u - 8) * 4;
    }
  }
  auto stage_unit = [&](int g) {
    const int buf = (g >> 2) & 1, kh = g & 3;
#pragma unroll
    for (int i = 0; i < 2; ++i)
      load_lds16(gbase[i] + g * 16, &Sb[buf][(cb_[i] + kh) * 512]);
  };

  // prologue: units 0..6 (tile0 q0-3, tile1 q0-2) = 14 loads/wave in flight
#pragma unroll
  for (int g = 0; g < 7; ++g) stage_unit(g);
  asm volatile("s_waitcnt vmcnt(6)" ::: "memory");   // tile 0 landed
  __builtin_amdgcn_s_barrier();
  asm volatile("" ::: "memory");

  for (int it = 0; it < 6; ++it) {
#pragma unroll
    for (int p = 0; p < 8; ++p) {
      const int buf = p >> 2;          // phases 0-3: tile 2it; 4-7: tile 2it+1
      const int kh = p & 3;
      // fragment ds_reads (compiler inserts lgkmcnt before MFMA use)
      bf16x8 af[4], bfr[2];
#pragma unroll
      for (int mi = 0; mi < 4; ++mi)
        af[mi] = *(const bf16x8*)&Sb[buf][((wm * 4 + mi) * 4 + kh) * 512 + l * 8];
#pragma unroll
      for (int ni = 0; ni < 2; ++ni)
        bfr[ni] = *(const bf16x8*)&Sb[buf][(32 + (wn * 2 + ni) * 4 + kh) * 512 + l * 8];
      // stage one quarter-unit (overwrites chunk read at phase p-1)
      const int g = 8 * it + 7 + p;
      if (g < 48) stage_unit(g);
      asm volatile("" ::: "memory");
      __builtin_amdgcn_s_barrier();
      asm volatile("" ::: "memory");
      __builtin_amdgcn_s_setprio(1);
#pragma unroll
      for (int mi = 0; mi < 4; ++mi)
#pragma unroll
        for (int ni = 0; ni < 2; ++ni)
          acc[mi][ni] = __builtin_amdgcn_mfma_f32_32x32x16_bf16(
              af[mi], bfr[ni], acc[mi][ni], 0, 0, 0);
      __builtin_amdgcn_s_setprio(0);
      // counted waits BEFORE trailing barrier (cross-wave visibility):
      // end p3 gates tile 2it+1; end p7 gates tile 2it+2; 3 units = 6 loads.
      if (p == 3) {
        if (it == 5) asm volatile("s_waitcnt vmcnt(0)" ::: "memory");
        else         asm volatile("s_waitcnt vmcnt(6)" ::: "memory");
      } else if (p == 7 && it < 5) {
        asm volatile("s_waitcnt vmcnt(6)" ::: "memory");
      }
      asm volatile("" ::: "memory");
      __builtin_amdgcn_s_barrier();
      asm volatile("" ::: "memory");
    }
  }

#pragma unroll
  for (int mi = 0; mi < 4; ++mi) {
    const int rowb = m0 + wm * 128 + mi * 32 + 4 * lh;
#pragma unroll
    for (int ni = 0; ni < 2; ++ni) {
      const int col = n0 + wn * 64 + ni * 32 + l31;
      const float bv = bias[col];
      if (col < 1536) {
        const float mul = (col < C_) ? sc : 1.f;
#pragma unroll
        for (int r = 0; r < 16; ++r) {
          const int row = rowb + (r & 3) + 8 * (r >> 2);
          Cout[(size_t)row * N1_ + col] = f2bf((acc[mi][ni][r] + bv) * mul);
        }
      } else {
        const int x = col - 1536;
        const int h = x / 96, d = x % 96;
#pragma unroll
        for (int r = 0; r < 16; ++r) {
          const int row = rowb + (r & 3) + 8 * (r >> 2);
          const int bb = row >> 10, t = row & 1023;
          vt[((size_t)(bb * H_ + h) * D_ + d) * T_ + t] =
              f2bf(acc[mi][ni][r] + bv);
        }
      }
    }
  }
}

// ---------------------------------------------------------------------------
// bf16 MFMA GEMM (R9 structure) — retained for the proj GEMM only.
// 3-buffer / 2-ahead pipeline with counted vmcnt + raw s_barrier.
// ---------------------------------------------------------------------------
template <int WM32, bool OUTF32, bool VSCAT>
__global__ __launch_bounds__(256, WM32 == 2 ? 3 : 4) void gemm_mfma_kernel(
    const unsigned short* __restrict__ A, const unsigned short* __restrict__ Bt,
    const float* __restrict__ bias, void* __restrict__ Cout,
    unsigned short* __restrict__ vt, int N,
    int sc_lim, float sc, int mmask, int mshift) {
  constexpr int AS2 = 2 * WM32;        // A 32-row blocks per tile
  constexpr int NCH = AS2 * 2 + 8;     // 1KB chunks per buffer
  constexpr int CPW = NCH / 4;         // chunks staged per wave
  __shared__ __align__(16) unsigned short Sb[3][NCH * 512];
  const int tid = threadIdx.x;
  const int w = tid >> 6, l = tid & 63;
  const int l31 = l & 31, lh = l >> 5;
  const int bid = blockIdx.x;
  const int m0 = (bid & mmask) * (AS2 * 32), n0 = (bid >> mshift) * 128;
  const int wrb = (w >> 1) * WM32;     // wave A-block base
  const int wnb = (w & 1) * 2;         // wave B-block base

  f32x16 acc[WM32][2];
#pragma unroll
  for (int i = 0; i < WM32; ++i)
#pragma unroll
    for (int j = 0; j < 2; ++j)
#pragma unroll
      for (int r = 0; r < 16; ++r) acc[i][j][r] = 0.f;

  const unsigned short* gp[CPW];
#pragma unroll
  for (int i = 0; i < CPW; ++i) {
    const int c = w * CPW + i;
    const int pr = c >> 1, kh = c & 1;
    gp[i] = (pr < AS2)
        ? A  + (size_t)(m0 + pr * 32 + l31) * KD_ + kh * 16 + lh * 8
        : Bt + (size_t)(n0 + (pr - AS2) * 32 + l31) * KD_ + kh * 16 + lh * 8;
  }

  // prologue: stage tiles 0 and 1 into buffers 0,1
#pragma unroll
  for (int t = 0; t < 2; ++t)
#pragma unroll
    for (int i = 0; i < CPW; ++i) {
      load_lds16(gp[i], &Sb[t][(w * CPW + i) * 512]);
      gp[i] += 32;
    }

  int cur = 0, stg = 2;
  for (int k0 = 0; k0 < KD_; k0 += 32) {
    if (k0 + 32 < KD_) {
      if constexpr (CPW == 4) asm volatile("s_waitcnt vmcnt(4)" ::: "memory");
      else                    asm volatile("s_waitcnt vmcnt(3)" ::: "memory");
    } else {
      asm volatile("s_waitcnt vmcnt(0)" ::: "memory");
    }
    __builtin_amdgcn_s_barrier();
    asm volatile("" ::: "memory");  // pin: no mem op crosses the barrier

    if (k0 + 64 < KD_) {
#pragma unroll
      for (int i = 0; i < CPW; ++i) {
        load_lds16(gp[i], &Sb[stg][(w * CPW + i) * 512]);
        gp[i] += 32;
      }
    }

#pragma unroll
    for (int kh = 0; kh < 2; ++kh) {
      bf16x8 af[WM32], bfr[2];
#pragma unroll
      for (int mi = 0; mi < WM32; ++mi)
        af[mi] = *(const bf16x8*)&Sb[cur][((wrb + mi) * 2 + kh) * 512 + l * 8];
#pragma unroll
      for (int ni = 0; ni < 2; ++ni)
        bfr[ni] = *(const bf16x8*)&Sb[cur][((AS2 + wnb + ni) * 2 + kh) * 512 + l * 8];
#pragma unroll
      for (int mi = 0; mi < WM32; ++mi)
#pragma unroll
        for (int ni = 0; ni < 2; ++ni)
          acc[mi][ni] = __builtin_amdgcn_mfma_f32_32x32x16_bf16(
              af[mi], bfr[ni], acc[mi][ni], 0, 0, 0);
    }
    cur = (cur == 2) ? 0 : cur + 1;
    stg = (stg == 2) ? 0 : stg + 1;
  }

  const bool vblock = VSCAT && (n0 >= 1536);
#pragma unroll
  for (int mi = 0; mi < WM32; ++mi) {
    const int rowb = m0 + (wrb + mi) * 32 + 4 * lh;
#pragma unroll
    for (int ni = 0; ni < 2; ++ni) {
      const int col = n0 + (wnb + ni) * 32 + l31;
      const float bv = bias[col];
      if (!vblock) {
        const float mul = (col < sc_lim) ? sc : 1.f;
#pragma unroll
        for (int r = 0; r < 16; ++r) {
          const int row = rowb + (r & 3) + 8 * (r >> 2);
          float v = (acc[mi][ni][r] + bv) * mul;
          if (OUTF32)
            ((float*)Cout)[(size_t)row * N + col] = v;
          else
            ((unsigned short*)Cout)[(size_t)row * N + col] = f2bf(v);
        }
      } else {
        const int x = col - 1536;
        const int h = x / 96, d = x % 96;
#pragma unroll
        for (int r = 0; r < 16; ++r) {
          const int row = rowb + (r & 3) + 8 * (r >> 2);
          const int bb = row >> 10, t = row & 1023;
          vt[((size_t)(bb * H_ + h) * D_ + d) * T_ + t] =
              f2bf(acc[mi][ni][r] + bv);
        }
      }
    }
  }
}

// ---------------------------------------------------------------------------
// Flash causal attention (unchanged): bf16 MFMA 16x16x32, max-free softmax
// (Q pre-scaled), l via ones-MFMA, paired q-tiles (17 key-tiles/block),
// K/V double-buffered LDS, XCD swizzle bh = id & 63.
// ---------------------------------------------------------------------------
__global__ __launch_bounds__(256) void attn_mfma_kernel(
    const unsigned short* __restrict__ qkv,  // [8192][2304], Q pre-scaled
    const unsigned short* __restrict__ vt,   // [64][96][1024]
    unsigned short* __restrict__ y) {        // [8192][768]
  __shared__ __align__(16) unsigned short KV[2][24 * 512];  // 48 KB
  __shared__ __align__(16) unsigned short Pt[4][16][72];    // pad 64->72

  const int tid = threadIdx.x;
  const int w = tid >> 6, l = tid & 63;
  const int lm = l & 15, lq = l >> 4;
  const int bh = blockIdx.x & 63, pi = blockIdx.x >> 6;
  const int b = bh >> 3, h = bh & 7;
  const size_t bT = (size_t)b * T_;

  bf16x8 onef;
#pragma unroll
  for (int i = 0; i < 8; ++i) onef[i] = (__bf16)1.0f;

  auto issue = [&](int j0, int buf) {
#pragma unroll
    for (int i = 0; i < 6; ++i) {
      const int c = w * 6 + i;
      const unsigned short* g;
      if (c < 12) {
        const int kc = c >> 2, nb = c & 3;
        g = qkv + (bT + j0 + nb * 16 + lm) * N1_ + C_ + h * D_ + kc * 32 + lq * 8;
      } else {
        const int cv = c - 12;
        const int db = cv >> 1, vc = cv & 1;
        g = vt + ((size_t)bh * D_ + db * 16 + lm) * T_ + j0 + vc * 32 + lq * 8;
      }
      load_lds16(g, &KV[buf][c * 512]);
    }
  };

  int cur = 0;
  issue(0, 0);

  for (int half = 0; half < 2; ++half) {
    const int qt = half ? (15 - pi) : pi;
    const int q0 = qt * 64;

    bf16x8 qf[3];
    {
      const unsigned short* qp =
          qkv + (bT + q0 + w * 16 + lm) * N1_ + h * D_ + lq * 8;
      qf[0] = *(const bf16x8*)(qp);
      qf[1] = *(const bf16x8*)(qp + 32);
      qf[2] = *(const bf16x8*)(qp + 64);
    }
    f32x4 o[7];
#pragma unroll
    for (int i = 0; i < 7; ++i) o[i] = (f32x4){0.f, 0.f, 0.f, 0.f};

    for (int jt = 0; jt <= qt; ++jt) {
      __syncthreads();
      if (jt < qt)          issue((jt + 1) * 64, cur ^ 1);
      else if (half == 0)   issue(0, cur ^ 1);

      const bool diag = (jt == qt);
#pragma unroll
      for (int nb = 0; nb < 4; ++nb) {
        if (diag && nb > w) {
#pragma unroll
          for (int r = 0; r < 4; ++r)
            Pt[w][lq * 4 + r][nb * 16 + lm] = 0;
          continue;
        }
        f32x4 a = (f32x4){0.f, 0.f, 0.f, 0.f};
#pragma unroll
        for (int kc = 0; kc < 3; ++kc) {
          bf16x8 kf = *(const bf16x8*)&KV[cur][(kc * 4 + nb) * 512 + l * 8];
          a = __builtin_amdgcn_mfma_f32_16x16x32_bf16(qf[kc], kf, a, 0, 0, 0);
        }
#pragma unroll
        for (int r = 0; r < 4; ++r) {
          float s = a[r];
          if (diag && (nb * 16 + lm > w * 16 + lq * 4 + r)) s = -INFINITY;
          Pt[w][lq * 4 + r][nb * 16 + lm] = f2bf(__expf(s));
        }
      }

      bf16x8 pf0 = *(const bf16x8*)&Pt[w][lm][lq * 8];
      bf16x8 pf1 = *(const bf16x8*)&Pt[w][lm][32 + lq * 8];
#pragma unroll
      for (int db = 0; db < 6; ++db) {
        bf16x8 vf0 = *(const bf16x8*)&KV[cur][(12 + db * 2 + 0) * 512 + l * 8];
        bf16x8 vf1 = *(const bf16x8*)&KV[cur][(12 + db * 2 + 1) * 512 + l * 8];
        o[db] = __builtin_amdgcn_mfma_f32_16x16x32_bf16(pf0, vf0, o[db], 0, 0, 0);
        o[db] = __builtin_amdgcn_mfma_f32_16x16x32_bf16(pf1, vf1, o[db], 0, 0, 0);
      }
      o[6] = __builtin_amdgcn_mfma_f32_16x16x32_bf16(pf0, onef, o[6], 0, 0, 0);
      o[6] = __builtin_amdgcn_mfma_f32_16x16x32_bf16(pf1, onef, o[6], 0, 0, 0);
      cur ^= 1;
    }

#pragma unroll
    for (int r = 0; r < 4; ++r) {
      const float inv = 1.f / o[6][r];
      const size_t row = bT + q0 + w * 16 + lq * 4 + r;
#pragma unroll
      for (int db = 0; db < 6; ++db)
        y[row * C_ + h * D_ + db * 16 + lm] = f2bf(o[db][r] * inv);
    }
  }
}

// ---------------------------------------------------------------------------
extern "C" void kernel_launch(void* const* d_in, const int* in_sizes, int n_in,
                              void* d_out, int out_size, void* d_ws, size_t ws_size,
                              hipStream_t stream) {
  const float* x      = (const float*)d_in[0];
  const float* W_attn = (const float*)d_in[1];
  const float* b_attn = (const float*)d_in[2];
  const float* W_proj = (const float*)d_in[3];
  const float* b_proj = (const float*)d_in[4];
  float* out = (float*)d_out;

  char* ws = (char*)d_ws;
  unsigned short* xb  = (unsigned short*)(ws);                    // 12.58 MB
  unsigned short* WaT = (unsigned short*)(ws + 12582912);         //  3.54 MB
  unsigned short* WpT = (unsigned short*)(ws + 16121856);         //  1.18 MB
  unsigned short* qkv = (unsigned short*)(ws + 17301504);         // 37.75 MB
  unsigned short* vt  = (unsigned short*)(ws + 55050240);         // 12.58 MB
  unsigned short* yb  = (unsigned short*)(ws + 67633152);         // 12.58 MB

  const float qscale = 0.10206207261596577f;  // 1/sqrt(96)

  // fused prep: x cast (6144 blocks) + both W transposes (2304 blocks)
  prep_kernel<<<6144 + 2304, 256, 0, stream>>>(x, xb, W_attn, WaT, W_proj, WpT);

  // qkv = x @ W_attn + b_attn: 256x256 tiles, 8-phase schedule, 288 blocks
  gemm256_kernel<<<(M_ / 256) * (N1_ / 256), 512, 0, stream>>>(
      xb, WaT, b_attn, qkv, vt, qscale);
  // attn: 512 blocks, bh = id & 63 for XCD locality
  attn_mfma_kernel<<<8 * B_ * H_, 256, 0, stream>>>(qkv, vt, yb);
  // proj: 64x128 tiles, 128 m-panels
  gemm_mfma_kernel<1, true, false><<<(C_ / 128) * (M_ / 64), 256, 0, stream>>>(
      yb, WpT, b_proj, out, nullptr, C_, 0, 1.f, 127, 7);
}

// Round 4
// 213.687 us; speedup vs baseline: 1.0930x; 1.0504x over previous
//
#include <hip/hip_runtime.h>
#include <math.h>

#define B_ 8
#define T_ 1024
#define C_ 768
#define H_ 8
#define D_ 96
#define M_ (B_ * T_)     // 8192 tokens
#define N1_ (3 * C_)     // 2304
#define KD_ 768          // K of both GEMMs

typedef __bf16 bf16x8 __attribute__((ext_vector_type(8)));
typedef float f32x4 __attribute__((ext_vector_type(4)));
typedef float f32x16 __attribute__((ext_vector_type(16)));

__device__ __forceinline__ unsigned short f2bf(float f) {
  unsigned int u = __float_as_uint(f);
  u += 0x7FFF + ((u >> 16) & 1);          // round-to-nearest-even
  return (unsigned short)(u >> 16);
}

// async global->LDS, 16B per lane; LDS dest = uniform base + lane*16
__device__ __forceinline__ void load_lds16(const void* g, void* l) {
  __builtin_amdgcn_global_load_lds(
      (const __attribute__((address_space(1))) unsigned int*)g,
      (__attribute__((address_space(3))) unsigned int*)l, 16, 0, 0);
}

// ---------------------------------------------------------------------------
// Fused prep: blocks 0..6143 cast x to bf16 (1024 elems each);
// blocks 6144.. transpose W_attn / W_proj to [N][K] bf16.
// ---------------------------------------------------------------------------
__global__ __launch_bounds__(256) void prep_kernel(
    const float* __restrict__ x, unsigned short* __restrict__ xb,
    const float* __restrict__ Wa, unsigned short* __restrict__ WaT,
    const float* __restrict__ Wp, unsigned short* __restrict__ WpT) {
  __shared__ float Lt[32][33];
  int bid = blockIdx.x;
  if (bid < 6144) {
    int i = (bid * 256 + threadIdx.x) * 4;
    float4 v = *(const float4*)(x + i);
    ushort4 o;
    o.x = f2bf(v.x); o.y = f2bf(v.y); o.z = f2bf(v.z); o.w = f2bf(v.w);
    *(ushort4*)(xb + i) = o;
    return;
  }
  bid -= 6144;
  const float* W; unsigned short* WT; int Nd;
  if (bid < 1728) { W = Wa; WT = WaT; Nd = N1_; }
  else            { W = Wp; WT = WpT; Nd = C_; bid -= 1728; }
  const int r0 = (bid % 24) * 32;   // Kd
  const int c0 = (bid / 24) * 32;   // Nd
#pragma unroll
  for (int i = 0; i < 4; ++i) {
    int e = threadIdx.x + 256 * i;
    int r = e >> 5, c = e & 31;
    Lt[r][c] = W[(size_t)(r0 + r) * Nd + c0 + c];
  }
  __syncthreads();
#pragma unroll
  for (int i = 0; i < 4; ++i) {
    int e = threadIdx.x + 256 * i;
    int rr = e >> 5, cc = e & 31;
    WT[(size_t)(c0 + rr) * KD_ + r0 + cc] = f2bf(Lt[cc][rr]);
  }
}

// ---------------------------------------------------------------------------
// R12: 256x256 QKV GEMM, 8-phase schedule + COALESCED swizzled staging.
// R11 post-mortem: all prior variants staged with row=l&31 / 32B-per-row
// scatter -> 32 half-line VMEM requests per gload_lds; three different
// schedules all pinned at 70-90us -> the per-load request cost, not wait
// placement, is the wall. Fixes (T2 both-sides swizzle, rule #21):
//  - LDS tile layout row-major [row][BK=64] (128B/row). Each 1KB wave-load
//    now reads 8 CONTIGUOUS 128B segments (8 rows x full BK): lane l ->
//    row +=(l>>3), 16B chunk (l&7)^(l>>3) (pre-swizzled GLOBAL source;
//    LDS dest stays lane-linear as global_load_lds requires).
//  - Frag ds_read_b128: row l31, chunk (2q+lh)^(l31&7) -> rows 0..7 cover
//    all 8 16B-slots of the 32-bank window => 2-way conflict = free (m136).
//  - Staging unit = 16KB row-range (A-half0/A-half1/B-half0/B-half1 per
//    K-tile; 16 loads = 2/wave). Row-range units + 2 buffers would force a
//    per-tile drain, so: 9-slot x 16KB LDS RING (144KB), lookahead 5
//    (stage unit g=p+5 at phase p). Ring-9 WAR check (stage phase >= last
//    read + 1): u=0: 4T-5 >= 4T-8 ok; u=1: 4T-4 >= 4T-8 ok; u=2: 4T-3 >=
//    4T-4 ok; u=3: 4T-2 >= 4T-4 ok. RAW gate once per tile, end of phase
//    4T+3: newer-than-needed = 1 unit = 2 loads -> vmcnt(2) (vmcnt(0) only
//    before the final tile). Prologue: units 0..4, vmcnt(2).
//  - Phase body unchanged: {6 ds_read frags; stage 1 unit; barrier;
//    setprio(1) 8x mfma_32x32x16 setprio(0); [gate]; barrier}.
//  - Grid 288 = 8 XCD x (4m x 9n); tail (288 on 256 CUs) accepted for now.
// Epilogue: bias + q-scale (col<768); V cols (>=1536) scatter to vt[bh][d][t].
// C/D frag: col = lane&31, row = (r&3)+8*(r>>2)+4*(lane>>5)  [m74/m101].
// ---------------------------------------------------------------------------
__global__ __launch_bounds__(512, 2) void gemm256_kernel(
    const unsigned short* __restrict__ A, const unsigned short* __restrict__ Bt,
    const float* __restrict__ bias, unsigned short* __restrict__ Cout,
    unsigned short* __restrict__ vt, float sc) {
  __shared__ __align__(16) unsigned short Sb[9 * 8192];  // 144 KB ring
  const int tid = threadIdx.x;
  const int w = tid >> 6, l = tid & 63;
  const int l31 = l & 31, lh = l >> 5;
  const int wm = w >> 2, wn = w & 3;

  const int bid = blockIdx.x;
  const int xcd = bid & 7, j = bid >> 3;         // 8 XCDs x 36 tiles
  const int m0 = (xcd * 4 + (j & 3)) * 256;      // 4 m-panels per XCD
  const int n0 = (j >> 2) * 256;                 // 9 n-panels

  f32x16 acc[4][2];
#pragma unroll
  for (int mi = 0; mi < 4; ++mi)
#pragma unroll
    for (int ni = 0; ni < 2; ++ni)
#pragma unroll
      for (int r = 0; r < 16; ++r) acc[mi][ni][r] = 0.f;

  // staging bases: lane l covers row += (l>>3), pre-swizzled chunk
  // (l&7)^(l>>3) (16B units; 8 ushorts). Unit types: 0=A rows 0-127,
  // 1=A rows 128-255, 2=B rows 0-127, 3=B rows 128-255.
  const int srow = 16 * w + (l >> 3);
  const int skoff = 8 * ((l & 7) ^ (l >> 3));
  const unsigned short* puA0 = A  + (size_t)(m0 + srow) * KD_ + skoff;
  const unsigned short* puA1 = A  + (size_t)(m0 + 128 + srow) * KD_ + skoff;
  const unsigned short* puB0 = Bt + (size_t)(n0 + srow) * KD_ + skoff;
  const unsigned short* puB1 = Bt + (size_t)(n0 + 128 + srow) * KD_ + skoff;

  // stage unit g (tile g>>2, type g&3) into ring slot: 2 loads/wave,
  // LDS dest lane-linear (slot*16KB + w*2KB + i*1KB + l*16B).
  auto stage_unit = [&](int g, int slot) {
    const int u = g & 3, Tg = g >> 2;
    const unsigned short* base =
        (u == 0) ? puA0 : (u == 1) ? puA1 : (u == 2) ? puB0 : puB1;
    const unsigned short* p0 = base + Tg * 64;
#pragma unroll
    for (int i = 0; i < 2; ++i)
      load_lds16(p0 + (size_t)i * (8 * KD_),
                 &Sb[slot * 8192 + w * 1024 + i * 512 + l * 8]);
  };

  // prologue: units 0..4 -> slots 0..4 (10 loads/wave in flight)
#pragma unroll
  for (int g = 0; g < 5; ++g) stage_unit(g, g);
  asm volatile("s_waitcnt vmcnt(2)" ::: "memory");   // units 0..3 landed
  __builtin_amdgcn_s_barrier();
  asm volatile("" ::: "memory");

  int sA = wm;              // ring slot of this wave's A unit (4T+wm)%9
  int sB = 2 + (wn >> 1);   // ring slot of this wave's B unit
  int sg = 5;               // next stage slot (g%9)

  for (int T = 0; T < 12; ++T) {
#pragma unroll
    for (int q = 0; q < 4; ++q) {
      // frag reads: row-major [row][64] + XOR swizzle; 2-way conflict (free)
      const int kterm = 8 * ((2 * q + lh) ^ (l31 & 7));
      bf16x8 af[4], bfr[2];
#pragma unroll
      for (int mi = 0; mi < 4; ++mi)
        af[mi] = *(const bf16x8*)&Sb[sA * 8192 + (mi * 32 + l31) * 64 + kterm];
#pragma unroll
      for (int ni = 0; ni < 2; ++ni)
        bfr[ni] = *(const bf16x8*)&Sb[sB * 8192 +
                                      ((wn & 1) * 64 + ni * 32 + l31) * 64 + kterm];
      // stage unit g = 4T+q+5 (u=(q+1)&3 is compile-time per unrolled q)
      {
        const int g = 4 * T + q + 5;
        if (g < 48) {
          stage_unit(g, sg);
          sg = (sg == 8) ? 0 : sg + 1;
        }
      }
      asm volatile("" ::: "memory");
      __builtin_amdgcn_s_barrier();
      asm volatile("" ::: "memory");
      __builtin_amdgcn_s_setprio(1);
#pragma unroll
      for (int mi = 0; mi < 4; ++mi)
#pragma unroll
        for (int ni = 0; ni < 2; ++ni)
          acc[mi][ni] = __builtin_amdgcn_mfma_f32_32x32x16_bf16(
              af[mi], bfr[ni], acc[mi][ni], 0, 0, 0);
      __builtin_amdgcn_s_setprio(0);
      // RAW gate before next tile: allow only the 1 newest unit (2 loads)
      if (q == 3 && T < 11) {
        if (T == 10) asm volatile("s_waitcnt vmcnt(0)" ::: "memory");
        else         asm volatile("s_waitcnt vmcnt(2)" ::: "memory");
      }
      asm volatile("" ::: "memory");
      __builtin_amdgcn_s_barrier();
      asm volatile("" ::: "memory");
    }
    sA += 4; if (sA >= 9) sA -= 9;
    sB += 4; if (sB >= 9) sB -= 9;
  }

#pragma unroll
  for (int mi = 0; mi < 4; ++mi) {
    const int rowb = m0 + wm * 128 + mi * 32 + 4 * lh;
#pragma unroll
    for (int ni = 0; ni < 2; ++ni) {
      const int col = n0 + wn * 64 + ni * 32 + l31;
      const float bv = bias[col];
      if (col < 1536) {
        const float mul = (col < C_) ? sc : 1.f;
#pragma unroll
        for (int r = 0; r < 16; ++r) {
          const int row = rowb + (r & 3) + 8 * (r >> 2);
          Cout[(size_t)row * N1_ + col] = f2bf((acc[mi][ni][r] + bv) * mul);
        }
      } else {
        const int x = col - 1536;
        const int h = x / 96, d = x % 96;
#pragma unroll
        for (int r = 0; r < 16; ++r) {
          const int row = rowb + (r & 3) + 8 * (r >> 2);
          const int bb = row >> 10, t = row & 1023;
          vt[((size_t)(bb * H_ + h) * D_ + d) * T_ + t] =
              f2bf(acc[mi][ni][r] + bv);
        }
      }
    }
  }
}

// ---------------------------------------------------------------------------
// bf16 MFMA GEMM (R9 structure) — retained for the proj GEMM only.
// 3-buffer / 2-ahead pipeline with counted vmcnt + raw s_barrier.
// ---------------------------------------------------------------------------
template <int WM32, bool OUTF32, bool VSCAT>
__global__ __launch_bounds__(256, WM32 == 2 ? 3 : 4) void gemm_mfma_kernel(
    const unsigned short* __restrict__ A, const unsigned short* __restrict__ Bt,
    const float* __restrict__ bias, void* __restrict__ Cout,
    unsigned short* __restrict__ vt, int N,
    int sc_lim, float sc, int mmask, int mshift) {
  constexpr int AS2 = 2 * WM32;        // A 32-row blocks per tile
  constexpr int NCH = AS2 * 2 + 8;     // 1KB chunks per buffer
  constexpr int CPW = NCH / 4;         // chunks staged per wave
  __shared__ __align__(16) unsigned short Sb[3][NCH * 512];
  const int tid = threadIdx.x;
  const int w = tid >> 6, l = tid & 63;
  const int l31 = l & 31, lh = l >> 5;
  const int bid = blockIdx.x;
  const int m0 = (bid & mmask) * (AS2 * 32), n0 = (bid >> mshift) * 128;
  const int wrb = (w >> 1) * WM32;     // wave A-block base
  const int wnb = (w & 1) * 2;         // wave B-block base

  f32x16 acc[WM32][2];
#pragma unroll
  for (int i = 0; i < WM32; ++i)
#pragma unroll
    for (int j = 0; j < 2; ++j)
#pragma unroll
      for (int r = 0; r < 16; ++r) acc[i][j][r] = 0.f;

  const unsigned short* gp[CPW];
#pragma unroll
  for (int i = 0; i < CPW; ++i) {
    const int c = w * CPW + i;
    const int pr = c >> 1, kh = c & 1;
    gp[i] = (pr < AS2)
        ? A  + (size_t)(m0 + pr * 32 + l31) * KD_ + kh * 16 + lh * 8
        : Bt + (size_t)(n0 + (pr - AS2) * 32 + l31) * KD_ + kh * 16 + lh * 8;
  }

  // prologue: stage tiles 0 and 1 into buffers 0,1
#pragma unroll
  for (int t = 0; t < 2; ++t)
#pragma unroll
    for (int i = 0; i < CPW; ++i) {
      load_lds16(gp[i], &Sb[t][(w * CPW + i) * 512]);
      gp[i] += 32;
    }

  int cur = 0, stg = 2;
  for (int k0 = 0; k0 < KD_; k0 += 32) {
    if (k0 + 32 < KD_) {
      if constexpr (CPW == 4) asm volatile("s_waitcnt vmcnt(4)" ::: "memory");
      else                    asm volatile("s_waitcnt vmcnt(3)" ::: "memory");
    } else {
      asm volatile("s_waitcnt vmcnt(0)" ::: "memory");
    }
    __builtin_amdgcn_s_barrier();
    asm volatile("" ::: "memory");  // pin: no mem op crosses the barrier

    if (k0 + 64 < KD_) {
#pragma unroll
      for (int i = 0; i < CPW; ++i) {
        load_lds16(gp[i], &Sb[stg][(w * CPW + i) * 512]);
        gp[i] += 32;
      }
    }

#pragma unroll
    for (int kh = 0; kh < 2; ++kh) {
      bf16x8 af[WM32], bfr[2];
#pragma unroll
      for (int mi = 0; mi < WM32; ++mi)
        af[mi] = *(const bf16x8*)&Sb[cur][((wrb + mi) * 2 + kh) * 512 + l * 8];
#pragma unroll
      for (int ni = 0; ni < 2; ++ni)
        bfr[ni] = *(const bf16x8*)&Sb[cur][((AS2 + wnb + ni) * 2 + kh) * 512 + l * 8];
#pragma unroll
      for (int mi = 0; mi < WM32; ++mi)
#pragma unroll
        for (int ni = 0; ni < 2; ++ni)
          acc[mi][ni] = __builtin_amdgcn_mfma_f32_32x32x16_bf16(
              af[mi], bfr[ni], acc[mi][ni], 0, 0, 0);
    }
    cur = (cur == 2) ? 0 : cur + 1;
    stg = (stg == 2) ? 0 : stg + 1;
  }

  const bool vblock = VSCAT && (n0 >= 1536);
#pragma unroll
  for (int mi = 0; mi < WM32; ++mi) {
    const int rowb = m0 + (wrb + mi) * 32 + 4 * lh;
#pragma unroll
    for (int ni = 0; ni < 2; ++ni) {
      const int col = n0 + (wnb + ni) * 32 + l31;
      const float bv = bias[col];
      if (!vblock) {
        const float mul = (col < sc_lim) ? sc : 1.f;
#pragma unroll
        for (int r = 0; r < 16; ++r) {
          const int row = rowb + (r & 3) + 8 * (r >> 2);
          float v = (acc[mi][ni][r] + bv) * mul;
          if (OUTF32)
            ((float*)Cout)[(size_t)row * N + col] = v;
          else
            ((unsigned short*)Cout)[(size_t)row * N + col] = f2bf(v);
        }
      } else {
        const int x = col - 1536;
        const int h = x / 96, d = x % 96;
#pragma unroll
        for (int r = 0; r < 16; ++r) {
          const int row = rowb + (r & 3) + 8 * (r >> 2);
          const int bb = row >> 10, t = row & 1023;
          vt[((size_t)(bb * H_ + h) * D_ + d) * T_ + t] =
              f2bf(acc[mi][ni][r] + bv);
        }
      }
    }
  }
}

// ---------------------------------------------------------------------------
// Flash causal attention (unchanged): bf16 MFMA 16x16x32, max-free softmax
// (Q pre-scaled), l via ones-MFMA, paired q-tiles (17 key-tiles/block),
// K/V double-buffered LDS, XCD swizzle bh = id & 63.
// ---------------------------------------------------------------------------
__global__ __launch_bounds__(256) void attn_mfma_kernel(
    const unsigned short* __restrict__ qkv,  // [8192][2304], Q pre-scaled
    const unsigned short* __restrict__ vt,   // [64][96][1024]
    unsigned short* __restrict__ y) {        // [8192][768]
  __shared__ __align__(16) unsigned short KV[2][24 * 512];  // 48 KB
  __shared__ __align__(16) unsigned short Pt[4][16][72];    // pad 64->72

  const int tid = threadIdx.x;
  const int w = tid >> 6, l = tid & 63;
  const int lm = l & 15, lq = l >> 4;
  const int bh = blockIdx.x & 63, pi = blockIdx.x >> 6;
  const int b = bh >> 3, h = bh & 7;
  const size_t bT = (size_t)b * T_;

  bf16x8 onef;
#pragma unroll
  for (int i = 0; i < 8; ++i) onef[i] = (__bf16)1.0f;

  auto issue = [&](int j0, int buf) {
#pragma unroll
    for (int i = 0; i < 6; ++i) {
      const int c = w * 6 + i;
      const unsigned short* g;
      if (c < 12) {
        const int kc = c >> 2, nb = c & 3;
        g = qkv + (bT + j0 + nb * 16 + lm) * N1_ + C_ + h * D_ + kc * 32 + lq * 8;
      } else {
        const int cv = c - 12;
        const int db = cv >> 1, vc = cv & 1;
        g = vt + ((size_t)bh * D_ + db * 16 + lm) * T_ + j0 + vc * 32 + lq * 8;
      }
      load_lds16(g, &KV[buf][c * 512]);
    }
  };

  int cur = 0;
  issue(0, 0);

  for (int half = 0; half < 2; ++half) {
    const int qt = half ? (15 - pi) : pi;
    const int q0 = qt * 64;

    bf16x8 qf[3];
    {
      const unsigned short* qp =
          qkv + (bT + q0 + w * 16 + lm) * N1_ + h * D_ + lq * 8;
      qf[0] = *(const bf16x8*)(qp);
      qf[1] = *(const bf16x8*)(qp + 32);
      qf[2] = *(const bf16x8*)(qp + 64);
    }
    f32x4 o[7];
#pragma unroll
    for (int i = 0; i < 7; ++i) o[i] = (f32x4){0.f, 0.f, 0.f, 0.f};

    for (int jt = 0; jt <= qt; ++jt) {
      __syncthreads();
      if (jt < qt)          issue((jt + 1) * 64, cur ^ 1);
      else if (half == 0)   issue(0, cur ^ 1);

      const bool diag = (jt == qt);
#pragma unroll
      for (int nb = 0; nb < 4; ++nb) {
        if (diag && nb > w) {
#pragma unroll
          for (int r = 0; r < 4; ++r)
            Pt[w][lq * 4 + r][nb * 16 + lm] = 0;
          continue;
        }
        f32x4 a = (f32x4){0.f, 0.f, 0.f, 0.f};
#pragma unroll
        for (int kc = 0; kc < 3; ++kc) {
          bf16x8 kf = *(const bf16x8*)&KV[cur][(kc * 4 + nb) * 512 + l * 8];
          a = __builtin_amdgcn_mfma_f32_16x16x32_bf16(qf[kc], kf, a, 0, 0, 0);
        }
#pragma unroll
        for (int r = 0; r < 4; ++r) {
          float s = a[r];
          if (diag && (nb * 16 + lm > w * 16 + lq * 4 + r)) s = -INFINITY;
          Pt[w][lq * 4 + r][nb * 16 + lm] = f2bf(__expf(s));
        }
      }

      bf16x8 pf0 = *(const bf16x8*)&Pt[w][lm][lq * 8];
      bf16x8 pf1 = *(const bf16x8*)&Pt[w][lm][32 + lq * 8];
#pragma unroll
      for (int db = 0; db < 6; ++db) {
        bf16x8 vf0 = *(const bf16x8*)&KV[cur][(12 + db * 2 + 0) * 512 + l * 8];
        bf16x8 vf1 = *(const bf16x8*)&KV[cur][(12 + db * 2 + 1) * 512 + l * 8];
        o[db] = __builtin_amdgcn_mfma_f32_16x16x32_bf16(pf0, vf0, o[db], 0, 0, 0);
        o[db] = __builtin_amdgcn_mfma_f32_16x16x32_bf16(pf1, vf1, o[db], 0, 0, 0);
      }
      o[6] = __builtin_amdgcn_mfma_f32_16x16x32_bf16(pf0, onef, o[6], 0, 0, 0);
      o[6] = __builtin_amdgcn_mfma_f32_16x16x32_bf16(pf1, onef, o[6], 0, 0, 0);
      cur ^= 1;
    }

#pragma unroll
    for (int r = 0; r < 4; ++r) {
      const float inv = 1.f / o[6][r];
      const size_t row = bT + q0 + w * 16 + lq * 4 + r;
#pragma unroll
      for (int db = 0; db < 6; ++db)
        y[row * C_ + h * D_ + db * 16 + lm] = f2bf(o[db][r] * inv);
    }
  }
}

// ---------------------------------------------------------------------------
extern "C" void kernel_launch(void* const* d_in, const int* in_sizes, int n_in,
                              void* d_out, int out_size, void* d_ws, size_t ws_size,
                              hipStream_t stream) {
  const float* x      = (const float*)d_in[0];
  const float* W_attn = (const float*)d_in[1];
  const float* b_attn = (const float*)d_in[2];
  const float* W_proj = (const float*)d_in[3];
  const float* b_proj = (const float*)d_in[4];
  float* out = (float*)d_out;

  char* ws = (char*)d_ws;
  unsigned short* xb  = (unsigned short*)(ws);                    // 12.58 MB
  unsigned short* WaT = (unsigned short*)(ws + 12582912);         //  3.54 MB
  unsigned short* WpT = (unsigned short*)(ws + 16121856);         //  1.18 MB
  unsigned short* qkv = (unsigned short*)(ws + 17301504);         // 37.75 MB
  unsigned short* vt  = (unsigned short*)(ws + 55050240);         // 12.58 MB
  unsigned short* yb  = (unsigned short*)(ws + 67633152);         // 12.58 MB

  const float qscale = 0.10206207261596577f;  // 1/sqrt(96)

  // fused prep: x cast (6144 blocks) + both W transposes (2304 blocks)
  prep_kernel<<<6144 + 2304, 256, 0, stream>>>(x, xb, W_attn, WaT, W_proj, WpT);

  // qkv = x @ W_attn + b_attn: 256x256 tiles, coalesced 8-phase, 288 blocks
  gemm256_kernel<<<(M_ / 256) * (N1_ / 256), 512, 0, stream>>>(
      xb, WaT, b_attn, qkv, vt, qscale);
  // attn: 512 blocks, bh = id & 63 for XCD locality
  attn_mfma_kernel<<<8 * B_ * H_, 256, 0, stream>>>(qkv, vt, yb);
  // proj: 64x128 tiles, 128 m-panels
  gemm_mfma_kernel<1, true, false><<<(C_ / 128) * (M_ / 64), 256, 0, stream>>>(
      yb, WpT, b_proj, out, nullptr, C_, 0, 1.f, 127, 7);
}

// Round 5
// 211.322 us; speedup vs baseline: 1.1053x; 1.0112x over previous
//
#include <hip/hip_runtime.h>
#include <math.h>

#define B_ 8
#define T_ 1024
#define C_ 768
#define H_ 8
#define D_ 96
#define M_ (B_ * T_)     // 8192 tokens
#define N1_ (3 * C_)     // 2304
#define KD_ 768          // K of both GEMMs

typedef __bf16 bf16x8 __attribute__((ext_vector_type(8)));
typedef float f32x4 __attribute__((ext_vector_type(4)));
typedef float f32x16 __attribute__((ext_vector_type(16)));

__device__ __forceinline__ unsigned short f2bf(float f) {
  unsigned int u = __float_as_uint(f);
  u += 0x7FFF + ((u >> 16) & 1);          // round-to-nearest-even
  return (unsigned short)(u >> 16);
}

// async global->LDS, 16B per lane; LDS dest = uniform base + lane*16
__device__ __forceinline__ void load_lds16(const void* g, void* l) {
  __builtin_amdgcn_global_load_lds(
      (const __attribute__((address_space(1))) unsigned int*)g,
      (__attribute__((address_space(3))) unsigned int*)l, 16, 0, 0);
}

// ---------------------------------------------------------------------------
// Fused prep: blocks 0..6143 cast x to bf16 (1024 elems each);
// blocks 6144.. transpose W_attn / W_proj to [N][K] bf16.
// ---------------------------------------------------------------------------
__global__ __launch_bounds__(256) void prep_kernel(
    const float* __restrict__ x, unsigned short* __restrict__ xb,
    const float* __restrict__ Wa, unsigned short* __restrict__ WaT,
    const float* __restrict__ Wp, unsigned short* __restrict__ WpT) {
  __shared__ float Lt[32][33];
  int bid = blockIdx.x;
  if (bid < 6144) {
    int i = (bid * 256 + threadIdx.x) * 4;
    float4 v = *(const float4*)(x + i);
    ushort4 o;
    o.x = f2bf(v.x); o.y = f2bf(v.y); o.z = f2bf(v.z); o.w = f2bf(v.w);
    *(ushort4*)(xb + i) = o;
    return;
  }
  bid -= 6144;
  const float* W; unsigned short* WT; int Nd;
  if (bid < 1728) { W = Wa; WT = WaT; Nd = N1_; }
  else            { W = Wp; WT = WpT; Nd = C_; bid -= 1728; }
  const int r0 = (bid % 24) * 32;   // Kd
  const int c0 = (bid / 24) * 32;   // Nd
#pragma unroll
  for (int i = 0; i < 4; ++i) {
    int e = threadIdx.x + 256 * i;
    int r = e >> 5, c = e & 31;
    Lt[r][c] = W[(size_t)(r0 + r) * Nd + c0 + c];
  }
  __syncthreads();
#pragma unroll
  for (int i = 0; i < 4; ++i) {
    int e = threadIdx.x + 256 * i;
    int rr = e >> 5, cc = e & 31;
    WT[(size_t)(c0 + rr) * KD_ + r0 + cc] = f2bf(Lt[cc][rr]);
  }
}

// ---------------------------------------------------------------------------
// R12 (kept): 256x256 QKV GEMM, 8-phase schedule + COALESCED swizzled staging.
//  - LDS tile layout row-major [row][BK=64] (128B/row). Each 1KB wave-load
//    reads 8 CONTIGUOUS 128B segments: lane l -> row += (l>>3), 16B chunk
//    (l&7)^(l>>3) (pre-swizzled GLOBAL source; LDS dest lane-linear).
//  - Frag ds_read_b128: row l31, chunk (2q+lh)^(l31&7); residual conflicts
//    ~2.65M cyc/dispatch (~6%) -- accepted.
//  - 9-slot x 16KB LDS RING (144KB), lookahead 5; RAW gate vmcnt(2) once
//    per tile; WAR safe by ring distance 9 (see R12 notes).
//  - Phase: {6 ds_read frags; stage 1 unit; barrier; setprio(1) 8x
//    mfma_32x32x16 setprio(0); [gate]; barrier}.
//  - Grid 288 = 8 XCD x (4m x 9n); known cost: 288-on-256 2-round tail.
// Epilogue: bias + q-scale (col<768); V cols (>=1536) scatter to vt[bh][d][t].
// C/D frag: col = lane&31, row = (r&3)+8*(r>>2)+4*(lane>>5)  [m74/m101].
// ---------------------------------------------------------------------------
__global__ __launch_bounds__(512, 2) void gemm256_kernel(
    const unsigned short* __restrict__ A, const unsigned short* __restrict__ Bt,
    const float* __restrict__ bias, unsigned short* __restrict__ Cout,
    unsigned short* __restrict__ vt, float sc) {
  __shared__ __align__(16) unsigned short Sb[9 * 8192];  // 144 KB ring
  const int tid = threadIdx.x;
  const int w = tid >> 6, l = tid & 63;
  const int l31 = l & 31, lh = l >> 5;
  const int wm = w >> 2, wn = w & 3;

  const int bid = blockIdx.x;
  const int xcd = bid & 7, j = bid >> 3;         // 8 XCDs x 36 tiles
  const int m0 = (xcd * 4 + (j & 3)) * 256;      // 4 m-panels per XCD
  const int n0 = (j >> 2) * 256;                 // 9 n-panels

  f32x16 acc[4][2];
#pragma unroll
  for (int mi = 0; mi < 4; ++mi)
#pragma unroll
    for (int ni = 0; ni < 2; ++ni)
#pragma unroll
      for (int r = 0; r < 16; ++r) acc[mi][ni][r] = 0.f;

  // staging bases: lane l covers row += (l>>3), pre-swizzled chunk
  // (l&7)^(l>>3) (16B units; 8 ushorts). Unit types: 0=A rows 0-127,
  // 1=A rows 128-255, 2=B rows 0-127, 3=B rows 128-255.
  const int srow = 16 * w + (l >> 3);
  const int skoff = 8 * ((l & 7) ^ (l >> 3));
  const unsigned short* puA0 = A  + (size_t)(m0 + srow) * KD_ + skoff;
  const unsigned short* puA1 = A  + (size_t)(m0 + 128 + srow) * KD_ + skoff;
  const unsigned short* puB0 = Bt + (size_t)(n0 + srow) * KD_ + skoff;
  const unsigned short* puB1 = Bt + (size_t)(n0 + 128 + srow) * KD_ + skoff;

  // stage unit g (tile g>>2, type g&3) into ring slot: 2 loads/wave,
  // LDS dest lane-linear (slot*16KB + w*2KB + i*1KB + l*16B).
  auto stage_unit = [&](int g, int slot) {
    const int u = g & 3, Tg = g >> 2;
    const unsigned short* base =
        (u == 0) ? puA0 : (u == 1) ? puA1 : (u == 2) ? puB0 : puB1;
    const unsigned short* p0 = base + Tg * 64;
#pragma unroll
    for (int i = 0; i < 2; ++i)
      load_lds16(p0 + (size_t)i * (8 * KD_),
                 &Sb[slot * 8192 + w * 1024 + i * 512 + l * 8]);
  };

  // prologue: units 0..4 -> slots 0..4 (10 loads/wave in flight)
#pragma unroll
  for (int g = 0; g < 5; ++g) stage_unit(g, g);
  asm volatile("s_waitcnt vmcnt(2)" ::: "memory");   // units 0..3 landed
  __builtin_amdgcn_s_barrier();
  asm volatile("" ::: "memory");

  int sA = wm;              // ring slot of this wave's A unit (4T+wm)%9
  int sB = 2 + (wn >> 1);   // ring slot of this wave's B unit
  int sg = 5;               // next stage slot (g%9)

  for (int T = 0; T < 12; ++T) {
#pragma unroll
    for (int q = 0; q < 4; ++q) {
      // frag reads: row-major [row][64] + XOR swizzle
      const int kterm = 8 * ((2 * q + lh) ^ (l31 & 7));
      bf16x8 af[4], bfr[2];
#pragma unroll
      for (int mi = 0; mi < 4; ++mi)
        af[mi] = *(const bf16x8*)&Sb[sA * 8192 + (mi * 32 + l31) * 64 + kterm];
#pragma unroll
      for (int ni = 0; ni < 2; ++ni)
        bfr[ni] = *(const bf16x8*)&Sb[sB * 8192 +
                                      ((wn & 1) * 64 + ni * 32 + l31) * 64 + kterm];
      // stage unit g = 4T+q+5
      {
        const int g = 4 * T + q + 5;
        if (g < 48) {
          stage_unit(g, sg);
          sg = (sg == 8) ? 0 : sg + 1;
        }
      }
      asm volatile("" ::: "memory");
      __builtin_amdgcn_s_barrier();
      asm volatile("" ::: "memory");
      __builtin_amdgcn_s_setprio(1);
#pragma unroll
      for (int mi = 0; mi < 4; ++mi)
#pragma unroll
        for (int ni = 0; ni < 2; ++ni)
          acc[mi][ni] = __builtin_amdgcn_mfma_f32_32x32x16_bf16(
              af[mi], bfr[ni], acc[mi][ni], 0, 0, 0);
      __builtin_amdgcn_s_setprio(0);
      // RAW gate before next tile: allow only the 1 newest unit (2 loads)
      if (q == 3 && T < 11) {
        if (T == 10) asm volatile("s_waitcnt vmcnt(0)" ::: "memory");
        else         asm volatile("s_waitcnt vmcnt(2)" ::: "memory");
      }
      asm volatile("" ::: "memory");
      __builtin_amdgcn_s_barrier();
      asm volatile("" ::: "memory");
    }
    sA += 4; if (sA >= 9) sA -= 9;
    sB += 4; if (sB >= 9) sB -= 9;
  }

#pragma unroll
  for (int mi = 0; mi < 4; ++mi) {
    const int rowb = m0 + wm * 128 + mi * 32 + 4 * lh;
#pragma unroll
    for (int ni = 0; ni < 2; ++ni) {
      const int col = n0 + wn * 64 + ni * 32 + l31;
      const float bv = bias[col];
      if (col < 1536) {
        const float mul = (col < C_) ? sc : 1.f;
#pragma unroll
        for (int r = 0; r < 16; ++r) {
          const int row = rowb + (r & 3) + 8 * (r >> 2);
          Cout[(size_t)row * N1_ + col] = f2bf((acc[mi][ni][r] + bv) * mul);
        }
      } else {
        const int x = col - 1536;
        const int h = x / 96, d = x % 96;
#pragma unroll
        for (int r = 0; r < 16; ++r) {
          const int row = rowb + (r & 3) + 8 * (r >> 2);
          const int bb = row >> 10, t = row & 1023;
          vt[((size_t)(bb * H_ + h) * D_ + d) * T_ + t] =
              f2bf(acc[mi][ni][r] + bv);
        }
      }
    }
  }
}

// ---------------------------------------------------------------------------
// bf16 MFMA GEMM (R9 structure): 3-buffer / 2-ahead pipeline, counted vmcnt.
// R13: now used for proj with WM32=2 (128x128 tile, intensity 64 FLOP/byte,
// 48KB LDS -> 3 blk/CU, grid 384 all-resident, no tail). The 64x128 WM32=1
// proj ran 71us = 137 TF -- worst per-FLOP kernel in the pipeline; the
// WM32=2 structure sustained 414 TF on QKV (R9).
// ---------------------------------------------------------------------------
template <int WM32, bool OUTF32, bool VSCAT>
__global__ __launch_bounds__(256, WM32 == 2 ? 3 : 4) void gemm_mfma_kernel(
    const unsigned short* __restrict__ A, const unsigned short* __restrict__ Bt,
    const float* __restrict__ bias, void* __restrict__ Cout,
    unsigned short* __restrict__ vt, int N,
    int sc_lim, float sc, int mmask, int mshift) {
  constexpr int AS2 = 2 * WM32;        // A 32-row blocks per tile
  constexpr int NCH = AS2 * 2 + 8;     // 1KB chunks per buffer
  constexpr int CPW = NCH / 4;         // chunks staged per wave
  __shared__ __align__(16) unsigned short Sb[3][NCH * 512];
  const int tid = threadIdx.x;
  const int w = tid >> 6, l = tid & 63;
  const int l31 = l & 31, lh = l >> 5;
  const int bid = blockIdx.x;
  const int m0 = (bid & mmask) * (AS2 * 32), n0 = (bid >> mshift) * 128;
  const int wrb = (w >> 1) * WM32;     // wave A-block base
  const int wnb = (w & 1) * 2;         // wave B-block base

  f32x16 acc[WM32][2];
#pragma unroll
  for (int i = 0; i < WM32; ++i)
#pragma unroll
    for (int j = 0; j < 2; ++j)
#pragma unroll
      for (int r = 0; r < 16; ++r) acc[i][j][r] = 0.f;

  const unsigned short* gp[CPW];
#pragma unroll
  for (int i = 0; i < CPW; ++i) {
    const int c = w * CPW + i;
    const int pr = c >> 1, kh = c & 1;
    gp[i] = (pr < AS2)
        ? A  + (size_t)(m0 + pr * 32 + l31) * KD_ + kh * 16 + lh * 8
        : Bt + (size_t)(n0 + (pr - AS2) * 32 + l31) * KD_ + kh * 16 + lh * 8;
  }

  // prologue: stage tiles 0 and 1 into buffers 0,1
#pragma unroll
  for (int t = 0; t < 2; ++t)
#pragma unroll
    for (int i = 0; i < CPW; ++i) {
      load_lds16(gp[i], &Sb[t][(w * CPW + i) * 512]);
      gp[i] += 32;
    }

  int cur = 0, stg = 2;
  for (int k0 = 0; k0 < KD_; k0 += 32) {
    if (k0 + 32 < KD_) {
      if constexpr (CPW == 4) asm volatile("s_waitcnt vmcnt(4)" ::: "memory");
      else                    asm volatile("s_waitcnt vmcnt(3)" ::: "memory");
    } else {
      asm volatile("s_waitcnt vmcnt(0)" ::: "memory");
    }
    __builtin_amdgcn_s_barrier();
    asm volatile("" ::: "memory");  // pin: no mem op crosses the barrier

    if (k0 + 64 < KD_) {
#pragma unroll
      for (int i = 0; i < CPW; ++i) {
        load_lds16(gp[i], &Sb[stg][(w * CPW + i) * 512]);
        gp[i] += 32;
      }
    }

#pragma unroll
    for (int kh = 0; kh < 2; ++kh) {
      bf16x8 af[WM32], bfr[2];
#pragma unroll
      for (int mi = 0; mi < WM32; ++mi)
        af[mi] = *(const bf16x8*)&Sb[cur][((wrb + mi) * 2 + kh) * 512 + l * 8];
#pragma unroll
      for (int ni = 0; ni < 2; ++ni)
        bfr[ni] = *(const bf16x8*)&Sb[cur][((AS2 + wnb + ni) * 2 + kh) * 512 + l * 8];
#pragma unroll
      for (int mi = 0; mi < WM32; ++mi)
#pragma unroll
        for (int ni = 0; ni < 2; ++ni)
          acc[mi][ni] = __builtin_amdgcn_mfma_f32_32x32x16_bf16(
              af[mi], bfr[ni], acc[mi][ni], 0, 0, 0);
    }
    cur = (cur == 2) ? 0 : cur + 1;
    stg = (stg == 2) ? 0 : stg + 1;
  }

  const bool vblock = VSCAT && (n0 >= 1536);
#pragma unroll
  for (int mi = 0; mi < WM32; ++mi) {
    const int rowb = m0 + (wrb + mi) * 32 + 4 * lh;
#pragma unroll
    for (int ni = 0; ni < 2; ++ni) {
      const int col = n0 + (wnb + ni) * 32 + l31;
      const float bv = bias[col];
      if (!vblock) {
        const float mul = (col < sc_lim) ? sc : 1.f;
#pragma unroll
        for (int r = 0; r < 16; ++r) {
          const int row = rowb + (r & 3) + 8 * (r >> 2);
          float v = (acc[mi][ni][r] + bv) * mul;
          if (OUTF32)
            ((float*)Cout)[(size_t)row * N + col] = v;
          else
            ((unsigned short*)Cout)[(size_t)row * N + col] = f2bf(v);
        }
      } else {
        const int x = col - 1536;
        const int h = x / 96, d = x % 96;
#pragma unroll
        for (int r = 0; r < 16; ++r) {
          const int row = rowb + (r & 3) + 8 * (r >> 2);
          const int bb = row >> 10, t = row & 1023;
          vt[((size_t)(bb * H_ + h) * D_ + d) * T_ + t] =
              f2bf(acc[mi][ni][r] + bv);
        }
      }
    }
  }
}

// ---------------------------------------------------------------------------
// Flash causal attention (unchanged): bf16 MFMA 16x16x32, max-free softmax
// (Q pre-scaled), l via ones-MFMA, paired q-tiles (17 key-tiles/block),
// K/V double-buffered LDS, XCD swizzle bh = id & 63.
// ---------------------------------------------------------------------------
__global__ __launch_bounds__(256) void attn_mfma_kernel(
    const unsigned short* __restrict__ qkv,  // [8192][2304], Q pre-scaled
    const unsigned short* __restrict__ vt,   // [64][96][1024]
    unsigned short* __restrict__ y) {        // [8192][768]
  __shared__ __align__(16) unsigned short KV[2][24 * 512];  // 48 KB
  __shared__ __align__(16) unsigned short Pt[4][16][72];    // pad 64->72

  const int tid = threadIdx.x;
  const int w = tid >> 6, l = tid & 63;
  const int lm = l & 15, lq = l >> 4;
  const int bh = blockIdx.x & 63, pi = blockIdx.x >> 6;
  const int b = bh >> 3, h = bh & 7;
  const size_t bT = (size_t)b * T_;

  bf16x8 onef;
#pragma unroll
  for (int i = 0; i < 8; ++i) onef[i] = (__bf16)1.0f;

  auto issue = [&](int j0, int buf) {
#pragma unroll
    for (int i = 0; i < 6; ++i) {
      const int c = w * 6 + i;
      const unsigned short* g;
      if (c < 12) {
        const int kc = c >> 2, nb = c & 3;
        g = qkv + (bT + j0 + nb * 16 + lm) * N1_ + C_ + h * D_ + kc * 32 + lq * 8;
      } else {
        const int cv = c - 12;
        const int db = cv >> 1, vc = cv & 1;
        g = vt + ((size_t)bh * D_ + db * 16 + lm) * T_ + j0 + vc * 32 + lq * 8;
      }
      load_lds16(g, &KV[buf][c * 512]);
    }
  };

  int cur = 0;
  issue(0, 0);

  for (int half = 0; half < 2; ++half) {
    const int qt = half ? (15 - pi) : pi;
    const int q0 = qt * 64;

    bf16x8 qf[3];
    {
      const unsigned short* qp =
          qkv + (bT + q0 + w * 16 + lm) * N1_ + h * D_ + lq * 8;
      qf[0] = *(const bf16x8*)(qp);
      qf[1] = *(const bf16x8*)(qp + 32);
      qf[2] = *(const bf16x8*)(qp + 64);
    }
    f32x4 o[7];
#pragma unroll
    for (int i = 0; i < 7; ++i) o[i] = (f32x4){0.f, 0.f, 0.f, 0.f};

    for (int jt = 0; jt <= qt; ++jt) {
      __syncthreads();
      if (jt < qt)          issue((jt + 1) * 64, cur ^ 1);
      else if (half == 0)   issue(0, cur ^ 1);

      const bool diag = (jt == qt);
#pragma unroll
      for (int nb = 0; nb < 4; ++nb) {
        if (diag && nb > w) {
#pragma unroll
          for (int r = 0; r < 4; ++r)
            Pt[w][lq * 4 + r][nb * 16 + lm] = 0;
          continue;
        }
        f32x4 a = (f32x4){0.f, 0.f, 0.f, 0.f};
#pragma unroll
        for (int kc = 0; kc < 3; ++kc) {
          bf16x8 kf = *(const bf16x8*)&KV[cur][(kc * 4 + nb) * 512 + l * 8];
          a = __builtin_amdgcn_mfma_f32_16x16x32_bf16(qf[kc], kf, a, 0, 0, 0);
        }
#pragma unroll
        for (int r = 0; r < 4; ++r) {
          float s = a[r];
          if (diag && (nb * 16 + lm > w * 16 + lq * 4 + r)) s = -INFINITY;
          Pt[w][lq * 4 + r][nb * 16 + lm] = f2bf(__expf(s));
        }
      }

      bf16x8 pf0 = *(const bf16x8*)&Pt[w][lm][lq * 8];
      bf16x8 pf1 = *(const bf16x8*)&Pt[w][lm][32 + lq * 8];
#pragma unroll
      for (int db = 0; db < 6; ++db) {
        bf16x8 vf0 = *(const bf16x8*)&KV[cur][(12 + db * 2 + 0) * 512 + l * 8];
        bf16x8 vf1 = *(const bf16x8*)&KV[cur][(12 + db * 2 + 1) * 512 + l * 8];
        o[db] = __builtin_amdgcn_mfma_f32_16x16x32_bf16(pf0, vf0, o[db], 0, 0, 0);
        o[db] = __builtin_amdgcn_mfma_f32_16x16x32_bf16(pf1, vf1, o[db], 0, 0, 0);
      }
      o[6] = __builtin_amdgcn_mfma_f32_16x16x32_bf16(pf0, onef, o[6], 0, 0, 0);
      o[6] = __builtin_amdgcn_mfma_f32_16x16x32_bf16(pf1, onef, o[6], 0, 0, 0);
      cur ^= 1;
    }

#pragma unroll
    for (int r = 0; r < 4; ++r) {
      const float inv = 1.f / o[6][r];
      const size_t row = bT + q0 + w * 16 + lq * 4 + r;
#pragma unroll
      for (int db = 0; db < 6; ++db)
        y[row * C_ + h * D_ + db * 16 + lm] = f2bf(o[db][r] * inv);
    }
  }
}

// ---------------------------------------------------------------------------
extern "C" void kernel_launch(void* const* d_in, const int* in_sizes, int n_in,
                              void* d_out, int out_size, void* d_ws, size_t ws_size,
                              hipStream_t stream) {
  const float* x      = (const float*)d_in[0];
  const float* W_attn = (const float*)d_in[1];
  const float* b_attn = (const float*)d_in[2];
  const float* W_proj = (const float*)d_in[3];
  const float* b_proj = (const float*)d_in[4];
  float* out = (float*)d_out;

  char* ws = (char*)d_ws;
  unsigned short* xb  = (unsigned short*)(ws);                    // 12.58 MB
  unsigned short* WaT = (unsigned short*)(ws + 12582912);         //  3.54 MB
  unsigned short* WpT = (unsigned short*)(ws + 16121856);         //  1.18 MB
  unsigned short* qkv = (unsigned short*)(ws + 17301504);         // 37.75 MB
  unsigned short* vt  = (unsigned short*)(ws + 55050240);         // 12.58 MB
  unsigned short* yb  = (unsigned short*)(ws + 67633152);         // 12.58 MB

  const float qscale = 0.10206207261596577f;  // 1/sqrt(96)

  // fused prep: x cast (6144 blocks) + both W transposes (2304 blocks)
  prep_kernel<<<6144 + 2304, 256, 0, stream>>>(x, xb, W_attn, WaT, W_proj, WpT);

  // qkv = x @ W_attn + b_attn: 256x256 tiles, coalesced 8-phase, 288 blocks
  gemm256_kernel<<<(M_ / 256) * (N1_ / 256), 512, 0, stream>>>(
      xb, WaT, b_attn, qkv, vt, qscale);
  // attn: 512 blocks, bh = id & 63 for XCD locality
  attn_mfma_kernel<<<8 * B_ * H_, 256, 0, stream>>>(qkv, vt, yb);
  // proj: 128x128 tiles (WM32=2), 64m x 6n = 384 blocks, 3 blk/CU, no tail
  gemm_mfma_kernel<2, true, false><<<(C_ / 128) * (M_ / 128), 256, 0, stream>>>(
      yb, WpT, b_proj, out, nullptr, C_, 0, 1.f, 63, 6);
}

// Round 6
// 193.023 us; speedup vs baseline: 1.2100x; 1.0948x over previous
//
#include <hip/hip_runtime.h>
#include <math.h>

#define B_ 8
#define T_ 1024
#define C_ 768
#define H_ 8
#define D_ 96
#define M_ (B_ * T_)     // 8192 tokens
#define N1_ (3 * C_)     // 2304
#define KD_ 768          // K of both GEMMs

typedef __bf16 bf16x8 __attribute__((ext_vector_type(8)));
typedef float f32x4 __attribute__((ext_vector_type(4)));
typedef float f32x16 __attribute__((ext_vector_type(16)));

__device__ __forceinline__ unsigned short f2bf(float f) {
  unsigned int u = __float_as_uint(f);
  u += 0x7FFF + ((u >> 16) & 1);          // round-to-nearest-even
  return (unsigned short)(u >> 16);
}

// async global->LDS, 16B per lane; LDS dest = uniform base + lane*16
__device__ __forceinline__ void load_lds16(const void* g, void* l) {
  __builtin_amdgcn_global_load_lds(
      (const __attribute__((address_space(1))) unsigned int*)g,
      (__attribute__((address_space(3))) unsigned int*)l, 16, 0, 0);
}

// ---------------------------------------------------------------------------
// Fused prep: blocks 0..6143 cast x to bf16 (1024 elems each);
// blocks 6144.. transpose W_attn / W_proj to [N][K] bf16.
// ---------------------------------------------------------------------------
__global__ __launch_bounds__(256) void prep_kernel(
    const float* __restrict__ x, unsigned short* __restrict__ xb,
    const float* __restrict__ Wa, unsigned short* __restrict__ WaT,
    const float* __restrict__ Wp, unsigned short* __restrict__ WpT) {
  __shared__ float Lt[32][33];
  int bid = blockIdx.x;
  if (bid < 6144) {
    int i = (bid * 256 + threadIdx.x) * 4;
    float4 v = *(const float4*)(x + i);
    ushort4 o;
    o.x = f2bf(v.x); o.y = f2bf(v.y); o.z = f2bf(v.z); o.w = f2bf(v.w);
    *(ushort4*)(xb + i) = o;
    return;
  }
  bid -= 6144;
  const float* W; unsigned short* WT; int Nd;
  if (bid < 1728) { W = Wa; WT = WaT; Nd = N1_; }
  else            { W = Wp; WT = WpT; Nd = C_; bid -= 1728; }
  const int r0 = (bid % 24) * 32;   // Kd
  const int c0 = (bid / 24) * 32;   // Nd
#pragma unroll
  for (int i = 0; i < 4; ++i) {
    int e = threadIdx.x + 256 * i;
    int r = e >> 5, c = e & 31;
    Lt[r][c] = W[(size_t)(r0 + r) * Nd + c0 + c];
  }
  __syncthreads();
#pragma unroll
  for (int i = 0; i < 4; ++i) {
    int e = threadIdx.x + 256 * i;
    int rr = e >> 5, cc = e & 31;
    WT[(size_t)(c0 + rr) * KD_ + r0 + cc] = f2bf(Lt[cc][rr]);
  }
}

// ---------------------------------------------------------------------------
// R14: 128x128 bf16 MFMA GEMM = R9's 3-resident 3-buffer counted-vmcnt
// structure + R12's COALESCED both-sides-swizzled staging. Post-mortems:
// R9 (3 blk/CU, scattered 32B/row staging) = 70us; R12 (coalesced, but
// 1 blk/CU, 46% residency) = 68us. Each fix alone hits the same wall;
// this combines them.
//  - Staging: per wave 4 x 1KB gload_lds; each load = 16 CONSECUTIVE rows
//    x 64B (full BK=32). Lane l -> row (l>>2), 16B chunk (l&3)^((l>>2)&3)
//    pre-swizzled on the GLOBAL source; LDS dest lane-linear (rule #21:
//    source perm == read perm, both XOR by row&3).
//  - LDS layout: 16 loads/buffer = [A 128 rows | B 128 rows] x 64B rows.
//    Frag ds_read_b128 at (stack row R, chunk q=2*kh+lh):
//    idx = (R>>4)*512 + (R&15)*32 + (q^(R&3))*8. Known 4-way bank conflict
//    (rows mod 4 share slot) -- R12 showed coalescing win dominates it.
//  - 3 buffers x 16KB, stage 2 tiles ahead, vmcnt(4) gate per K-step
//    (vmcnt(0) final), one s_barrier per K-step. 48KB LDS + ~132 combined
//    regs -> ~3 blocks/CU resident: cross-block overlap hides per-phase
//    serialization (the R9 property R12 lost).
// Used for BOTH GEMMs (QKV: VSCAT scatters V cols to vt; proj: OUTF32).
// C/D frag: col = lane&31, row = (r&3)+8*(r>>2)+4*(lane>>5)  [m74/m101].
// ---------------------------------------------------------------------------
template <bool OUTF32, bool VSCAT>
__global__ __launch_bounds__(256, 4) void gemm_mfma_kernel(
    const unsigned short* __restrict__ A, const unsigned short* __restrict__ Bt,
    const float* __restrict__ bias, void* __restrict__ Cout,
    unsigned short* __restrict__ vt, int N,
    int sc_lim, float sc, int mmask, int mshift) {
  constexpr int NCH = 16;              // 1KB chunks per buffer (A 8 + B 8)
  constexpr int CPW = 4;               // chunks staged per wave
  __shared__ __align__(16) unsigned short Sb[3][NCH * 512];  // 3 x 16 KB
  const int tid = threadIdx.x;
  const int w = tid >> 6, l = tid & 63;
  const int l31 = l & 31, lh = l >> 5;
  const int bid = blockIdx.x;
  const int m0 = (bid & mmask) * 128, n0 = (bid >> mshift) * 128;
  const int wrb = (w >> 1) * 2;        // wave A-block base (32-row units)
  const int wnb = (w & 1) * 2;         // wave B-block base

  f32x16 acc[2][2];
#pragma unroll
  for (int i = 0; i < 2; ++i)
#pragma unroll
    for (int j = 0; j < 2; ++j)
#pragma unroll
      for (int r = 0; r < 16; ++r) acc[i][j][r] = 0.f;

  // coalesced staging pointers: load c covers stack rows [c*16, c*16+16)
  // (c<8 -> A rows, c>=8 -> B rows), lane l -> row +(l>>2), pre-swizzled
  // 16B chunk (l&3)^((l>>2)&3).
  const unsigned short* gp[CPW];
#pragma unroll
  for (int i = 0; i < CPW; ++i) {
    const int c = w * CPW + i;
    const int rr = (c & 7) * 16 + (l >> 2);
    const int ck = 8 * ((l & 3) ^ ((l >> 2) & 3));
    gp[i] = (c < 8) ? A  + (size_t)(m0 + rr) * KD_ + ck
                    : Bt + (size_t)(n0 + rr) * KD_ + ck;
  }

  // prologue: stage tiles 0 and 1 into buffers 0,1 (8 loads/wave in flight)
#pragma unroll
  for (int t = 0; t < 2; ++t)
#pragma unroll
    for (int i = 0; i < CPW; ++i) {
      load_lds16(gp[i], &Sb[t][(w * CPW + i) * 512]);
      gp[i] += 32;
    }

  // frag-read address helpers (see header comment)
  const int rhi = l31 >> 4;            // (R&31)>>4
  const int rlo = (l31 & 15) * 32;     // (R&15)*32 ushorts
  const int rx  = l31 & 3;             // R&3 (XOR term)

  int cur = 0, stg = 2;
  for (int k0 = 0; k0 < KD_; k0 += 32) {
    if (k0 + 32 < KD_) {
      asm volatile("s_waitcnt vmcnt(4)" ::: "memory");
    } else {
      asm volatile("s_waitcnt vmcnt(0)" ::: "memory");
    }
    __builtin_amdgcn_s_barrier();
    asm volatile("" ::: "memory");  // pin: no mem op crosses the barrier

    if (k0 + 64 < KD_) {
#pragma unroll
      for (int i = 0; i < CPW; ++i) {
        load_lds16(gp[i], &Sb[stg][(w * CPW + i) * 512]);
        gp[i] += 32;
      }
    }

#pragma unroll
    for (int kh = 0; kh < 2; ++kh) {
      const int q = 2 * kh + lh;       // 16B chunk index within 64B row
      bf16x8 af[2], bfr[2];
#pragma unroll
      for (int mi = 0; mi < 2; ++mi)
        af[mi] = *(const bf16x8*)
            &Sb[cur][((wrb + mi) * 2 + rhi) * 512 + rlo + ((q ^ rx)) * 8];
#pragma unroll
      for (int ni = 0; ni < 2; ++ni)
        bfr[ni] = *(const bf16x8*)
            &Sb[cur][(8 + (wnb + ni) * 2 + rhi) * 512 + rlo + ((q ^ rx)) * 8];
#pragma unroll
      for (int mi = 0; mi < 2; ++mi)
#pragma unroll
        for (int ni = 0; ni < 2; ++ni)
          acc[mi][ni] = __builtin_amdgcn_mfma_f32_32x32x16_bf16(
              af[mi], bfr[ni], acc[mi][ni], 0, 0, 0);
    }
    cur = (cur == 2) ? 0 : cur + 1;
    stg = (stg == 2) ? 0 : stg + 1;
  }

  const bool vblock = VSCAT && (n0 >= 1536);
#pragma unroll
  for (int mi = 0; mi < 2; ++mi) {
    const int rowb = m0 + (wrb + mi) * 32 + 4 * lh;
#pragma unroll
    for (int ni = 0; ni < 2; ++ni) {
      const int col = n0 + (wnb + ni) * 32 + l31;
      const float bv = bias[col];
      if (!vblock) {
        const float mul = (col < sc_lim) ? sc : 1.f;
#pragma unroll
        for (int r = 0; r < 16; ++r) {
          const int row = rowb + (r & 3) + 8 * (r >> 2);
          float v = (acc[mi][ni][r] + bv) * mul;
          if (OUTF32)
            ((float*)Cout)[(size_t)row * N + col] = v;
          else
            ((unsigned short*)Cout)[(size_t)row * N + col] = f2bf(v);
        }
      } else {
        const int x = col - 1536;
        const int h = x / 96, d = x % 96;
#pragma unroll
        for (int r = 0; r < 16; ++r) {
          const int row = rowb + (r & 3) + 8 * (r >> 2);
          const int bb = row >> 10, t = row & 1023;
          vt[((size_t)(bb * H_ + h) * D_ + d) * T_ + t] =
              f2bf(acc[mi][ni][r] + bv);
        }
      }
    }
  }
}

// ---------------------------------------------------------------------------
// Flash causal attention (unchanged): bf16 MFMA 16x16x32, max-free softmax
// (Q pre-scaled), l via ones-MFMA, paired q-tiles (17 key-tiles/block),
// K/V double-buffered LDS, XCD swizzle bh = id & 63.
// ---------------------------------------------------------------------------
__global__ __launch_bounds__(256) void attn_mfma_kernel(
    const unsigned short* __restrict__ qkv,  // [8192][2304], Q pre-scaled
    const unsigned short* __restrict__ vt,   // [64][96][1024]
    unsigned short* __restrict__ y) {        // [8192][768]
  __shared__ __align__(16) unsigned short KV[2][24 * 512];  // 48 KB
  __shared__ __align__(16) unsigned short Pt[4][16][72];    // pad 64->72

  const int tid = threadIdx.x;
  const int w = tid >> 6, l = tid & 63;
  const int lm = l & 15, lq = l >> 4;
  const int bh = blockIdx.x & 63, pi = blockIdx.x >> 6;
  const int b = bh >> 3, h = bh & 7;
  const size_t bT = (size_t)b * T_;

  bf16x8 onef;
#pragma unroll
  for (int i = 0; i < 8; ++i) onef[i] = (__bf16)1.0f;

  auto issue = [&](int j0, int buf) {
#pragma unroll
    for (int i = 0; i < 6; ++i) {
      const int c = w * 6 + i;
      const unsigned short* g;
      if (c < 12) {
        const int kc = c >> 2, nb = c & 3;
        g = qkv + (bT + j0 + nb * 16 + lm) * N1_ + C_ + h * D_ + kc * 32 + lq * 8;
      } else {
        const int cv = c - 12;
        const int db = cv >> 1, vc = cv & 1;
        g = vt + ((size_t)bh * D_ + db * 16 + lm) * T_ + j0 + vc * 32 + lq * 8;
      }
      load_lds16(g, &KV[buf][c * 512]);
    }
  };

  int cur = 0;
  issue(0, 0);

  for (int half = 0; half < 2; ++half) {
    const int qt = half ? (15 - pi) : pi;
    const int q0 = qt * 64;

    bf16x8 qf[3];
    {
      const unsigned short* qp =
          qkv + (bT + q0 + w * 16 + lm) * N1_ + h * D_ + lq * 8;
      qf[0] = *(const bf16x8*)(qp);
      qf[1] = *(const bf16x8*)(qp + 32);
      qf[2] = *(const bf16x8*)(qp + 64);
    }
    f32x4 o[7];
#pragma unroll
    for (int i = 0; i < 7; ++i) o[i] = (f32x4){0.f, 0.f, 0.f, 0.f};

    for (int jt = 0; jt <= qt; ++jt) {
      __syncthreads();
      if (jt < qt)          issue((jt + 1) * 64, cur ^ 1);
      else if (half == 0)   issue(0, cur ^ 1);

      const bool diag = (jt == qt);
#pragma unroll
      for (int nb = 0; nb < 4; ++nb) {
        if (diag && nb > w) {
#pragma unroll
          for (int r = 0; r < 4; ++r)
            Pt[w][lq * 4 + r][nb * 16 + lm] = 0;
          continue;
        }
        f32x4 a = (f32x4){0.f, 0.f, 0.f, 0.f};
#pragma unroll
        for (int kc = 0; kc < 3; ++kc) {
          bf16x8 kf = *(const bf16x8*)&KV[cur][(kc * 4 + nb) * 512 + l * 8];
          a = __builtin_amdgcn_mfma_f32_16x16x32_bf16(qf[kc], kf, a, 0, 0, 0);
        }
#pragma unroll
        for (int r = 0; r < 4; ++r) {
          float s = a[r];
          if (diag && (nb * 16 + lm > w * 16 + lq * 4 + r)) s = -INFINITY;
          Pt[w][lq * 4 + r][nb * 16 + lm] = f2bf(__expf(s));
        }
      }

      bf16x8 pf0 = *(const bf16x8*)&Pt[w][lm][lq * 8];
      bf16x8 pf1 = *(const bf16x8*)&Pt[w][lm][32 + lq * 8];
#pragma unroll
      for (int db = 0; db < 6; ++db) {
        bf16x8 vf0 = *(const bf16x8*)&KV[cur][(12 + db * 2 + 0) * 512 + l * 8];
        bf16x8 vf1 = *(const bf16x8*)&KV[cur][(12 + db * 2 + 1) * 512 + l * 8];
        o[db] = __builtin_amdgcn_mfma_f32_16x16x32_bf16(pf0, vf0, o[db], 0, 0, 0);
        o[db] = __builtin_amdgcn_mfma_f32_16x16x32_bf16(pf1, vf1, o[db], 0, 0, 0);
      }
      o[6] = __builtin_amdgcn_mfma_f32_16x16x32_bf16(pf0, onef, o[6], 0, 0, 0);
      o[6] = __builtin_amdgcn_mfma_f32_16x16x32_bf16(pf1, onef, o[6], 0, 0, 0);
      cur ^= 1;
    }

#pragma unroll
    for (int r = 0; r < 4; ++r) {
      const float inv = 1.f / o[6][r];
      const size_t row = bT + q0 + w * 16 + lq * 4 + r;
#pragma unroll
      for (int db = 0; db < 6; ++db)
        y[row * C_ + h * D_ + db * 16 + lm] = f2bf(o[db][r] * inv);
    }
  }
}

// ---------------------------------------------------------------------------
extern "C" void kernel_launch(void* const* d_in, const int* in_sizes, int n_in,
                              void* d_out, int out_size, void* d_ws, size_t ws_size,
                              hipStream_t stream) {
  const float* x      = (const float*)d_in[0];
  const float* W_attn = (const float*)d_in[1];
  const float* b_attn = (const float*)d_in[2];
  const float* W_proj = (const float*)d_in[3];
  const float* b_proj = (const float*)d_in[4];
  float* out = (float*)d_out;

  char* ws = (char*)d_ws;
  unsigned short* xb  = (unsigned short*)(ws);                    // 12.58 MB
  unsigned short* WaT = (unsigned short*)(ws + 12582912);         //  3.54 MB
  unsigned short* WpT = (unsigned short*)(ws + 16121856);         //  1.18 MB
  unsigned short* qkv = (unsigned short*)(ws + 17301504);         // 37.75 MB
  unsigned short* vt  = (unsigned short*)(ws + 55050240);         // 12.58 MB
  unsigned short* yb  = (unsigned short*)(ws + 67633152);         // 12.58 MB

  const float qscale = 0.10206207261596577f;  // 1/sqrt(96)

  // fused prep: x cast (6144 blocks) + both W transposes (2304 blocks)
  prep_kernel<<<6144 + 2304, 256, 0, stream>>>(x, xb, W_attn, WaT, W_proj, WpT);

  // qkv = x @ W_attn + b_attn: 128x128 tiles, coalesced staging, 1152 blocks
  gemm_mfma_kernel<false, true><<<(N1_ / 128) * (M_ / 128), 256, 0, stream>>>(
      xb, WaT, b_attn, qkv, vt, N1_, C_, qscale, 63, 6);
  // attn: 512 blocks, bh = id & 63 for XCD locality
  attn_mfma_kernel<<<8 * B_ * H_, 256, 0, stream>>>(qkv, vt, yb);
  // proj: 128x128 tiles, 64m x 6n = 384 blocks
  gemm_mfma_kernel<true, false><<<(C_ / 128) * (M_ / 128), 256, 0, stream>>>(
      yb, WpT, b_proj, out, nullptr, C_, 0, 1.f, 63, 6);
}

// Round 7
// 187.562 us; speedup vs baseline: 1.2453x; 1.0291x over previous
//
#include <hip/hip_runtime.h>
#include <math.h>

#define B_ 8
#define T_ 1024
#define C_ 768
#define H_ 8
#define D_ 96
#define M_ (B_ * T_)     // 8192 tokens
#define N1_ (3 * C_)     // 2304
#define KD_ 768          // K of both GEMMs

typedef __bf16 bf16x8 __attribute__((ext_vector_type(8)));
typedef float f32x4 __attribute__((ext_vector_type(4)));
typedef float f32x16 __attribute__((ext_vector_type(16)));

__device__ __forceinline__ unsigned short f2bf(float f) {
  unsigned int u = __float_as_uint(f);
  u += 0x7FFF + ((u >> 16) & 1);          // round-to-nearest-even
  return (unsigned short)(u >> 16);
}

// async global->LDS, 16B per lane; LDS dest = uniform base + lane*16
__device__ __forceinline__ void load_lds16(const void* g, void* l) {
  __builtin_amdgcn_global_load_lds(
      (const __attribute__((address_space(1))) unsigned int*)g,
      (__attribute__((address_space(3))) unsigned int*)l, 16, 0, 0);
}

// ---------------------------------------------------------------------------
// Fused prep: blocks 0..6143 cast x to bf16 (1024 elems each);
// blocks 6144.. transpose W_attn / W_proj to [N][K] bf16.
// ---------------------------------------------------------------------------
__global__ __launch_bounds__(256) void prep_kernel(
    const float* __restrict__ x, unsigned short* __restrict__ xb,
    const float* __restrict__ Wa, unsigned short* __restrict__ WaT,
    const float* __restrict__ Wp, unsigned short* __restrict__ WpT) {
  __shared__ float Lt[32][33];
  int bid = blockIdx.x;
  if (bid < 6144) {
    int i = (bid * 256 + threadIdx.x) * 4;
    float4 v = *(const float4*)(x + i);
    ushort4 o;
    o.x = f2bf(v.x); o.y = f2bf(v.y); o.z = f2bf(v.z); o.w = f2bf(v.w);
    *(ushort4*)(xb + i) = o;
    return;
  }
  bid -= 6144;
  const float* W; unsigned short* WT; int Nd;
  if (bid < 1728) { W = Wa; WT = WaT; Nd = N1_; }
  else            { W = Wp; WT = WpT; Nd = C_; bid -= 1728; }
  const int r0 = (bid % 24) * 32;   // Kd
  const int c0 = (bid / 24) * 32;   // Nd
#pragma unroll
  for (int i = 0; i < 4; ++i) {
    int e = threadIdx.x + 256 * i;
    int r = e >> 5, c = e & 31;
    Lt[r][c] = W[(size_t)(r0 + r) * Nd + c0 + c];
  }
  __syncthreads();
#pragma unroll
  for (int i = 0; i < 4; ++i) {
    int e = threadIdx.x + 256 * i;
    int rr = e >> 5, cc = e & 31;
    WT[(size_t)(c0 + rr) * KD_ + r0 + cc] = f2bf(Lt[cc][rr]);
  }
}

// ---------------------------------------------------------------------------
// R15: R14 structure, bank-conflict fix. R14's frag-read bank start was
// (R&1)*16 + (q^(R&3))*4 -- R&3 drives BOTH terms -> only 4 distinct
// 4-bank groups for 32 rows = 8-WAY conflict (10.6M cycles ~= 29% of
// kernel time, 2.94x LDS cost per m136). Fix: slot XOR on (R>>2)&3
// instead of R&3. Bank start (R&1)*16 + (q^((R>>2)&3))*4 covers all 8
// possible starts evenly -> 4-way (the floor for 32 rows of b128).
// Both sides change together (rule #21):
//  - stage: lane l global chunk = (l&3) ^ ((l>>4)&3)   [(R>>2)&3 == (l>>4)&3]
//  - read:  slot = q ^ ((l31>>2)&3)
// Involution: LDS slot s of row R holds chunk s^((R>>2)&3); reading slot
// q^((R>>2)&3) returns chunk q.
// Rest unchanged from R14: 128x128 tile, BK=32, 64B-segment coalesced
// gload_lds (16 rows x 64B per 1KB load), 3 buffers x 16KB, 2-ahead
// counted vmcnt(4), one s_barrier per K-step, ~3-4 blocks/CU resident.
// Used for BOTH GEMMs (QKV: VSCAT scatters V cols to vt; proj: OUTF32).
// C/D frag: col = lane&31, row = (r&3)+8*(r>>2)+4*(lane>>5)  [m74/m101].
// ---------------------------------------------------------------------------
template <bool OUTF32, bool VSCAT>
__global__ __launch_bounds__(256, 4) void gemm_mfma_kernel(
    const unsigned short* __restrict__ A, const unsigned short* __restrict__ Bt,
    const float* __restrict__ bias, void* __restrict__ Cout,
    unsigned short* __restrict__ vt, int N,
    int sc_lim, float sc, int mmask, int mshift) {
  constexpr int NCH = 16;              // 1KB chunks per buffer (A 8 + B 8)
  constexpr int CPW = 4;               // chunks staged per wave
  __shared__ __align__(16) unsigned short Sb[3][NCH * 512];  // 3 x 16 KB
  const int tid = threadIdx.x;
  const int w = tid >> 6, l = tid & 63;
  const int l31 = l & 31, lh = l >> 5;
  const int bid = blockIdx.x;
  const int m0 = (bid & mmask) * 128, n0 = (bid >> mshift) * 128;
  const int wrb = (w >> 1) * 2;        // wave A-block base (32-row units)
  const int wnb = (w & 1) * 2;         // wave B-block base

  f32x16 acc[2][2];
#pragma unroll
  for (int i = 0; i < 2; ++i)
#pragma unroll
    for (int j = 0; j < 2; ++j)
#pragma unroll
      for (int r = 0; r < 16; ++r) acc[i][j][r] = 0.f;

  // coalesced staging pointers: load c covers stack rows [c*16, c*16+16)
  // (c<8 -> A rows, c>=8 -> B rows), lane l -> row +(l>>2), pre-swizzled
  // 16B chunk (l&3)^((l>>4)&3)   [R15: was (l&3)^((l>>2)&3)].
  const unsigned short* gp[CPW];
#pragma unroll
  for (int i = 0; i < CPW; ++i) {
    const int c = w * CPW + i;
    const int rr = (c & 7) * 16 + (l >> 2);
    const int ck = 8 * ((l & 3) ^ ((l >> 4) & 3));
    gp[i] = (c < 8) ? A  + (size_t)(m0 + rr) * KD_ + ck
                    : Bt + (size_t)(n0 + rr) * KD_ + ck;
  }

  // prologue: stage tiles 0 and 1 into buffers 0,1 (8 loads/wave in flight)
#pragma unroll
  for (int t = 0; t < 2; ++t)
#pragma unroll
    for (int i = 0; i < CPW; ++i) {
      load_lds16(gp[i], &Sb[t][(w * CPW + i) * 512]);
      gp[i] += 32;
    }

  // frag-read address helpers (see header comment)
  const int rhi = l31 >> 4;            // (R&31)>>4
  const int rlo = (l31 & 15) * 32;     // (R&15)*32 ushorts
  const int rx  = (l31 >> 2) & 3;      // (R>>2)&3 (XOR term)  [R15]

  int cur = 0, stg = 2;
  for (int k0 = 0; k0 < KD_; k0 += 32) {
    if (k0 + 32 < KD_) {
      asm volatile("s_waitcnt vmcnt(4)" ::: "memory");
    } else {
      asm volatile("s_waitcnt vmcnt(0)" ::: "memory");
    }
    __builtin_amdgcn_s_barrier();
    asm volatile("" ::: "memory");  // pin: no mem op crosses the barrier

    if (k0 + 64 < KD_) {
#pragma unroll
      for (int i = 0; i < CPW; ++i) {
        load_lds16(gp[i], &Sb[stg][(w * CPW + i) * 512]);
        gp[i] += 32;
      }
    }

#pragma unroll
    for (int kh = 0; kh < 2; ++kh) {
      const int q = 2 * kh + lh;       // 16B chunk index within 64B row
      bf16x8 af[2], bfr[2];
#pragma unroll
      for (int mi = 0; mi < 2; ++mi)
        af[mi] = *(const bf16x8*)
            &Sb[cur][((wrb + mi) * 2 + rhi) * 512 + rlo + ((q ^ rx)) * 8];
#pragma unroll
      for (int ni = 0; ni < 2; ++ni)
        bfr[ni] = *(const bf16x8*)
            &Sb[cur][(8 + (wnb + ni) * 2 + rhi) * 512 + rlo + ((q ^ rx)) * 8];
#pragma unroll
      for (int mi = 0; mi < 2; ++mi)
#pragma unroll
        for (int ni = 0; ni < 2; ++ni)
          acc[mi][ni] = __builtin_amdgcn_mfma_f32_32x32x16_bf16(
              af[mi], bfr[ni], acc[mi][ni], 0, 0, 0);
    }
    cur = (cur == 2) ? 0 : cur + 1;
    stg = (stg == 2) ? 0 : stg + 1;
  }

  const bool vblock = VSCAT && (n0 >= 1536);
#pragma unroll
  for (int mi = 0; mi < 2; ++mi) {
    const int rowb = m0 + (wrb + mi) * 32 + 4 * lh;
#pragma unroll
    for (int ni = 0; ni < 2; ++ni) {
      const int col = n0 + (wnb + ni) * 32 + l31;
      const float bv = bias[col];
      if (!vblock) {
        const float mul = (col < sc_lim) ? sc : 1.f;
#pragma unroll
        for (int r = 0; r < 16; ++r) {
          const int row = rowb + (r & 3) + 8 * (r >> 2);
          float v = (acc[mi][ni][r] + bv) * mul;
          if (OUTF32)
            ((float*)Cout)[(size_t)row * N + col] = v;
          else
            ((unsigned short*)Cout)[(size_t)row * N + col] = f2bf(v);
        }
      } else {
        const int x = col - 1536;
        const int h = x / 96, d = x % 96;
#pragma unroll
        for (int r = 0; r < 16; ++r) {
          const int row = rowb + (r & 3) + 8 * (r >> 2);
          const int bb = row >> 10, t = row & 1023;
          vt[((size_t)(bb * H_ + h) * D_ + d) * T_ + t] =
              f2bf(acc[mi][ni][r] + bv);
        }
      }
    }
  }
}

// ---------------------------------------------------------------------------
// Flash causal attention (unchanged): bf16 MFMA 16x16x32, max-free softmax
// (Q pre-scaled), l via ones-MFMA, paired q-tiles (17 key-tiles/block),
// K/V double-buffered LDS, XCD swizzle bh = id & 63.
// ---------------------------------------------------------------------------
__global__ __launch_bounds__(256) void attn_mfma_kernel(
    const unsigned short* __restrict__ qkv,  // [8192][2304], Q pre-scaled
    const unsigned short* __restrict__ vt,   // [64][96][1024]
    unsigned short* __restrict__ y) {        // [8192][768]
  __shared__ __align__(16) unsigned short KV[2][24 * 512];  // 48 KB
  __shared__ __align__(16) unsigned short Pt[4][16][72];    // pad 64->72

  const int tid = threadIdx.x;
  const int w = tid >> 6, l = tid & 63;
  const int lm = l & 15, lq = l >> 4;
  const int bh = blockIdx.x & 63, pi = blockIdx.x >> 6;
  const int b = bh >> 3, h = bh & 7;
  const size_t bT = (size_t)b * T_;

  bf16x8 onef;
#pragma unroll
  for (int i = 0; i < 8; ++i) onef[i] = (__bf16)1.0f;

  auto issue = [&](int j0, int buf) {
#pragma unroll
    for (int i = 0; i < 6; ++i) {
      const int c = w * 6 + i;
      const unsigned short* g;
      if (c < 12) {
        const int kc = c >> 2, nb = c & 3;
        g = qkv + (bT + j0 + nb * 16 + lm) * N1_ + C_ + h * D_ + kc * 32 + lq * 8;
      } else {
        const int cv = c - 12;
        const int db = cv >> 1, vc = cv & 1;
        g = vt + ((size_t)bh * D_ + db * 16 + lm) * T_ + j0 + vc * 32 + lq * 8;
      }
      load_lds16(g, &KV[buf][c * 512]);
    }
  };

  int cur = 0;
  issue(0, 0);

  for (int half = 0; half < 2; ++half) {
    const int qt = half ? (15 - pi) : pi;
    const int q0 = qt * 64;

    bf16x8 qf[3];
    {
      const unsigned short* qp =
          qkv + (bT + q0 + w * 16 + lm) * N1_ + h * D_ + lq * 8;
      qf[0] = *(const bf16x8*)(qp);
      qf[1] = *(const bf16x8*)(qp + 32);
      qf[2] = *(const bf16x8*)(qp + 64);
    }
    f32x4 o[7];
#pragma unroll
    for (int i = 0; i < 7; ++i) o[i] = (f32x4){0.f, 0.f, 0.f, 0.f};

    for (int jt = 0; jt <= qt; ++jt) {
      __syncthreads();
      if (jt < qt)          issue((jt + 1) * 64, cur ^ 1);
      else if (half == 0)   issue(0, cur ^ 1);

      const bool diag = (jt == qt);
#pragma unroll
      for (int nb = 0; nb < 4; ++nb) {
        if (diag && nb > w) {
#pragma unroll
          for (int r = 0; r < 4; ++r)
            Pt[w][lq * 4 + r][nb * 16 + lm] = 0;
          continue;
        }
        f32x4 a = (f32x4){0.f, 0.f, 0.f, 0.f};
#pragma unroll
        for (int kc = 0; kc < 3; ++kc) {
          bf16x8 kf = *(const bf16x8*)&KV[cur][(kc * 4 + nb) * 512 + l * 8];
          a = __builtin_amdgcn_mfma_f32_16x16x32_bf16(qf[kc], kf, a, 0, 0, 0);
        }
#pragma unroll
        for (int r = 0; r < 4; ++r) {
          float s = a[r];
          if (diag && (nb * 16 + lm > w * 16 + lq * 4 + r)) s = -INFINITY;
          Pt[w][lq * 4 + r][nb * 16 + lm] = f2bf(__expf(s));
        }
      }

      bf16x8 pf0 = *(const bf16x8*)&Pt[w][lm][lq * 8];
      bf16x8 pf1 = *(const bf16x8*)&Pt[w][lm][32 + lq * 8];
#pragma unroll
      for (int db = 0; db < 6; ++db) {
        bf16x8 vf0 = *(const bf16x8*)&KV[cur][(12 + db * 2 + 0) * 512 + l * 8];
        bf16x8 vf1 = *(const bf16x8*)&KV[cur][(12 + db * 2 + 1) * 512 + l * 8];
        o[db] = __builtin_amdgcn_mfma_f32_16x16x32_bf16(pf0, vf0, o[db], 0, 0, 0);
        o[db] = __builtin_amdgcn_mfma_f32_16x16x32_bf16(pf1, vf1, o[db], 0, 0, 0);
      }
      o[6] = __builtin_amdgcn_mfma_f32_16x16x32_bf16(pf0, onef, o[6], 0, 0, 0);
      o[6] = __builtin_amdgcn_mfma_f32_16x16x32_bf16(pf1, onef, o[6], 0, 0, 0);
      cur ^= 1;
    }

#pragma unroll
    for (int r = 0; r < 4; ++r) {
      const float inv = 1.f / o[6][r];
      const size_t row = bT + q0 + w * 16 + lq * 4 + r;
#pragma unroll
      for (int db = 0; db < 6; ++db)
        y[row * C_ + h * D_ + db * 16 + lm] = f2bf(o[db][r] * inv);
    }
  }
}

// ---------------------------------------------------------------------------
extern "C" void kernel_launch(void* const* d_in, const int* in_sizes, int n_in,
                              void* d_out, int out_size, void* d_ws, size_t ws_size,
                              hipStream_t stream) {
  const float* x      = (const float*)d_in[0];
  const float* W_attn = (const float*)d_in[1];
  const float* b_attn = (const float*)d_in[2];
  const float* W_proj = (const float*)d_in[3];
  const float* b_proj = (const float*)d_in[4];
  float* out = (float*)d_out;

  char* ws = (char*)d_ws;
  unsigned short* xb  = (unsigned short*)(ws);                    // 12.58 MB
  unsigned short* WaT = (unsigned short*)(ws + 12582912);         //  3.54 MB
  unsigned short* WpT = (unsigned short*)(ws + 16121856);         //  1.18 MB
  unsigned short* qkv = (unsigned short*)(ws + 17301504);         // 37.75 MB
  unsigned short* vt  = (unsigned short*)(ws + 55050240);         // 12.58 MB
  unsigned short* yb  = (unsigned short*)(ws + 67633152);         // 12.58 MB

  const float qscale = 0.10206207261596577f;  // 1/sqrt(96)

  // fused prep: x cast (6144 blocks) + both W transposes (2304 blocks)
  prep_kernel<<<6144 + 2304, 256, 0, stream>>>(x, xb, W_attn, WaT, W_proj, WpT);

  // qkv = x @ W_attn + b_attn: 128x128 tiles, coalesced staging, 1152 blocks
  gemm_mfma_kernel<false, true><<<(N1_ / 128) * (M_ / 128), 256, 0, stream>>>(
      xb, WaT, b_attn, qkv, vt, N1_, C_, qscale, 63, 6);
  // attn: 512 blocks, bh = id & 63 for XCD locality
  attn_mfma_kernel<<<8 * B_ * H_, 256, 0, stream>>>(qkv, vt, yb);
  // proj: 128x128 tiles, 64m x 6n = 384 blocks
  gemm_mfma_kernel<true, false><<<(C_ / 128) * (M_ / 128), 256, 0, stream>>>(
      yb, WpT, b_proj, out, nullptr, C_, 0, 1.f, 63, 6);
}

// Round 8
// 184.602 us; speedup vs baseline: 1.2652x; 1.0160x over previous
//
#include <hip/hip_runtime.h>
#include <math.h>

#define B_ 8
#define T_ 1024
#define C_ 768
#define H_ 8
#define D_ 96
#define M_ (B_ * T_)     // 8192 tokens
#define N1_ (3 * C_)     // 2304
#define KD_ 768          // K of both GEMMs
#define QS_ 1536         // qkv row stride (Q+K only; V lives in vt)

typedef __bf16 bf16x8 __attribute__((ext_vector_type(8)));
typedef float f32x4 __attribute__((ext_vector_type(4)));
typedef float f32x16 __attribute__((ext_vector_type(16)));

__device__ __forceinline__ unsigned short f2bf(float f) {
  unsigned int u = __float_as_uint(f);
  u += 0x7FFF + ((u >> 16) & 1);          // round-to-nearest-even
  return (unsigned short)(u >> 16);
}

// async global->LDS, 16B per lane; LDS dest = uniform base + lane*16
__device__ __forceinline__ void load_lds16(const void* g, void* l) {
  __builtin_amdgcn_global_load_lds(
      (const __attribute__((address_space(1))) unsigned int*)g,
      (__attribute__((address_space(3))) unsigned int*)l, 16, 0, 0);
}

// ---------------------------------------------------------------------------
// Fused prep: blocks 0..6143 cast x to bf16 (1024 elems each);
// blocks 6144.. transpose W_attn / W_proj to [N][K] bf16.
// ---------------------------------------------------------------------------
__global__ __launch_bounds__(256) void prep_kernel(
    const float* __restrict__ x, unsigned short* __restrict__ xb,
    const float* __restrict__ Wa, unsigned short* __restrict__ WaT,
    const float* __restrict__ Wp, unsigned short* __restrict__ WpT) {
  __shared__ float Lt[32][33];
  int bid = blockIdx.x;
  if (bid < 6144) {
    int i = (bid * 256 + threadIdx.x) * 4;
    float4 v = *(const float4*)(x + i);
    ushort4 o;
    o.x = f2bf(v.x); o.y = f2bf(v.y); o.z = f2bf(v.z); o.w = f2bf(v.w);
    *(ushort4*)(xb + i) = o;
    return;
  }
  bid -= 6144;
  const float* W; unsigned short* WT; int Nd;
  if (bid < 1728) { W = Wa; WT = WaT; Nd = N1_; }
  else            { W = Wp; WT = WpT; Nd = C_; bid -= 1728; }
  const int r0 = (bid % 24) * 32;   // Kd
  const int c0 = (bid / 24) * 32;   // Nd
#pragma unroll
  for (int i = 0; i < 4; ++i) {
    int e = threadIdx.x + 256 * i;
    int r = e >> 5, c = e & 31;
    Lt[r][c] = W[(size_t)(r0 + r) * Nd + c0 + c];
  }
  __syncthreads();
#pragma unroll
  for (int i = 0; i < 4; ++i) {
    int e = threadIdx.x + 256 * i;
    int rr = e >> 5, cc = e & 31;
    WT[(size_t)(c0 + rr) * KD_ + r0 + cc] = f2bf(Lt[cc][rr]);
  }
}

// ---------------------------------------------------------------------------
// R16: R15 staging/swizzle (coalesced 64B segments, conflict-free XOR on
// (R>>2)&3, 0 measured conflicts) but back to the m97 2-BUFFER 32KB
// pipeline. Evidence: R8 (32KB) ran at ~2.1 blocks/CU occupancy; every
// 48KB 3-buffer variant (R9/R14/R15) at ~1.2. The 3rd buffer's extra
// pipeline depth measured NULL (R1: 70.2 vs 70.9) while costing a
// residency tier -- cross-block overlap (m114) is what hides per-phase
// latency, not lookahead depth. 32KB + 112 VGPR -> 4 blocks/CU.
// Pipeline per K-step: stage(next -> buf^1); ds_read frags(cur); MFMA;
// vmcnt(0); barrier. (T3-minimal recipe.)
// Staging: per wave 4 x 1KB gload_lds; each = 16 consecutive rows x 64B
// (full BK=32). Lane l -> row (l>>2), global 16B chunk (l&3)^((l>>4)&3);
// LDS dest lane-linear. Frag read slot q^((R>>2)&3) -- involution, 0 confl.
// Used for BOTH GEMMs (QKV: VSCAT scatters V cols to vt; proj: OUTF32).
// C/D frag: col = lane&31, row = (r&3)+8*(r>>2)+4*(lane>>5)  [m74/m101].
// ---------------------------------------------------------------------------
template <bool OUTF32, bool VSCAT>
__global__ __launch_bounds__(256, 4) void gemm_mfma_kernel(
    const unsigned short* __restrict__ A, const unsigned short* __restrict__ Bt,
    const float* __restrict__ bias, void* __restrict__ Cout,
    unsigned short* __restrict__ vt, int N,
    int sc_lim, float sc, int mmask, int mshift) {
  constexpr int NCH = 16;              // 1KB chunks per buffer (A 8 + B 8)
  constexpr int CPW = 4;               // chunks staged per wave
  __shared__ __align__(16) unsigned short Sb[2][NCH * 512];  // 2 x 16 KB
  const int tid = threadIdx.x;
  const int w = tid >> 6, l = tid & 63;
  const int l31 = l & 31, lh = l >> 5;
  const int bid = blockIdx.x;
  const int m0 = (bid & mmask) * 128, n0 = (bid >> mshift) * 128;
  const int wrb = (w >> 1) * 2;        // wave A-block base (32-row units)
  const int wnb = (w & 1) * 2;         // wave B-block base

  f32x16 acc[2][2];
#pragma unroll
  for (int i = 0; i < 2; ++i)
#pragma unroll
    for (int j = 0; j < 2; ++j)
#pragma unroll
      for (int r = 0; r < 16; ++r) acc[i][j][r] = 0.f;

  // coalesced staging pointers: load c covers stack rows [c*16, c*16+16)
  // (c<8 -> A rows, c>=8 -> B rows), lane l -> row +(l>>2), pre-swizzled
  // 16B chunk (l&3)^((l>>4)&3).
  const unsigned short* gp[CPW];
#pragma unroll
  for (int i = 0; i < CPW; ++i) {
    const int c = w * CPW + i;
    const int rr = (c & 7) * 16 + (l >> 2);
    const int ck = 8 * ((l & 3) ^ ((l >> 4) & 3));
    gp[i] = (c < 8) ? A  + (size_t)(m0 + rr) * KD_ + ck
                    : Bt + (size_t)(n0 + rr) * KD_ + ck;
  }

  // prologue: stage tile 0 into buffer 0
#pragma unroll
  for (int i = 0; i < CPW; ++i) {
    load_lds16(gp[i], &Sb[0][(w * CPW + i) * 512]);
    gp[i] += 32;
  }
  asm volatile("s_waitcnt vmcnt(0)" ::: "memory");
  __builtin_amdgcn_s_barrier();
  asm volatile("" ::: "memory");

  // frag-read address helpers
  const int rhi = l31 >> 4;            // (R&31)>>4
  const int rlo = (l31 & 15) * 32;     // (R&15)*32 ushorts
  const int rx  = (l31 >> 2) & 3;      // (R>>2)&3 (XOR term)

  int cur = 0;
  for (int k0 = 0; k0 < KD_; k0 += 32) {
    const bool more = (k0 + 32 < KD_);
    if (more) {
#pragma unroll
      for (int i = 0; i < CPW; ++i) {
        load_lds16(gp[i], &Sb[cur ^ 1][(w * CPW + i) * 512]);
        gp[i] += 32;
      }
    }

#pragma unroll
    for (int kh = 0; kh < 2; ++kh) {
      const int q = 2 * kh + lh;       // 16B chunk index within 64B row
      bf16x8 af[2], bfr[2];
#pragma unroll
      for (int mi = 0; mi < 2; ++mi)
        af[mi] = *(const bf16x8*)
            &Sb[cur][((wrb + mi) * 2 + rhi) * 512 + rlo + ((q ^ rx)) * 8];
#pragma unroll
      for (int ni = 0; ni < 2; ++ni)
        bfr[ni] = *(const bf16x8*)
            &Sb[cur][(8 + (wnb + ni) * 2 + rhi) * 512 + rlo + ((q ^ rx)) * 8];
#pragma unroll
      for (int mi = 0; mi < 2; ++mi)
#pragma unroll
        for (int ni = 0; ni < 2; ++ni)
          acc[mi][ni] = __builtin_amdgcn_mfma_f32_32x32x16_bf16(
              af[mi], bfr[ni], acc[mi][ni], 0, 0, 0);
    }

    if (more) {
      asm volatile("s_waitcnt vmcnt(0)" ::: "memory");
      asm volatile("" ::: "memory");
      __builtin_amdgcn_s_barrier();
      asm volatile("" ::: "memory");
    }
    cur ^= 1;
  }

  const bool vblock = VSCAT && (n0 >= 1536);
#pragma unroll
  for (int mi = 0; mi < 2; ++mi) {
    const int rowb = m0 + (wrb + mi) * 32 + 4 * lh;
#pragma unroll
    for (int ni = 0; ni < 2; ++ni) {
      const int col = n0 + (wnb + ni) * 32 + l31;
      const float bv = bias[col];
      if (!vblock) {
        const float mul = (col < sc_lim) ? sc : 1.f;
#pragma unroll
        for (int r = 0; r < 16; ++r) {
          const int row = rowb + (r & 3) + 8 * (r >> 2);
          float v = (acc[mi][ni][r] + bv) * mul;
          if (OUTF32)
            ((float*)Cout)[(size_t)row * N + col] = v;
          else
            ((unsigned short*)Cout)[(size_t)row * N + col] = f2bf(v);
        }
      } else {
        const int x = col - 1536;
        const int h = x / 96, d = x % 96;
#pragma unroll
        for (int r = 0; r < 16; ++r) {
          const int row = rowb + (r & 3) + 8 * (r >> 2);
          const int bb = row >> 10, t = row & 1023;
          vt[((size_t)(bb * H_ + h) * D_ + d) * T_ + t] =
              f2bf(acc[mi][ni][r] + bv);
        }
      }
    }
  }
}

// ---------------------------------------------------------------------------
// Flash causal attention: bf16 MFMA 16x16x32, max-free softmax (Q pre-
// scaled), l via ones-MFMA, paired q-tiles, K/V double-buffered LDS.
// R16: qkv row stride N1_ -> QS_ (V third of qkv no longer allocated).
// ---------------------------------------------------------------------------
__global__ __launch_bounds__(256) void attn_mfma_kernel(
    const unsigned short* __restrict__ qkv,  // [8192][QS_], Q pre-scaled
    const unsigned short* __restrict__ vt,   // [64][96][1024]
    unsigned short* __restrict__ y) {        // [8192][768]
  __shared__ __align__(16) unsigned short KV[2][24 * 512];  // 48 KB
  __shared__ __align__(16) unsigned short Pt[4][16][72];    // pad 64->72

  const int tid = threadIdx.x;
  const int w = tid >> 6, l = tid & 63;
  const int lm = l & 15, lq = l >> 4;
  const int bh = blockIdx.x & 63, pi = blockIdx.x >> 6;
  const int b = bh >> 3, h = bh & 7;
  const size_t bT = (size_t)b * T_;

  bf16x8 onef;
#pragma unroll
  for (int i = 0; i < 8; ++i) onef[i] = (__bf16)1.0f;

  auto issue = [&](int j0, int buf) {
#pragma unroll
    for (int i = 0; i < 6; ++i) {
      const int c = w * 6 + i;
      const unsigned short* g;
      if (c < 12) {
        const int kc = c >> 2, nb = c & 3;
        g = qkv + (bT + j0 + nb * 16 + lm) * QS_ + C_ + h * D_ + kc * 32 + lq * 8;
      } else {
        const int cv = c - 12;
        const int db = cv >> 1, vc = cv & 1;
        g = vt + ((size_t)bh * D_ + db * 16 + lm) * T_ + j0 + vc * 32 + lq * 8;
      }
      load_lds16(g, &KV[buf][c * 512]);
    }
  };

  int cur = 0;
  issue(0, 0);

  for (int half = 0; half < 2; ++half) {
    const int qt = half ? (15 - pi) : pi;
    const int q0 = qt * 64;

    bf16x8 qf[3];
    {
      const unsigned short* qp =
          qkv + (bT + q0 + w * 16 + lm) * QS_ + h * D_ + lq * 8;
      qf[0] = *(const bf16x8*)(qp);
      qf[1] = *(const bf16x8*)(qp + 32);
      qf[2] = *(const bf16x8*)(qp + 64);
    }
    f32x4 o[7];
#pragma unroll
    for (int i = 0; i < 7; ++i) o[i] = (f32x4){0.f, 0.f, 0.f, 0.f};

    for (int jt = 0; jt <= qt; ++jt) {
      __syncthreads();
      if (jt < qt)          issue((jt + 1) * 64, cur ^ 1);
      else if (half == 0)   issue(0, cur ^ 1);

      const bool diag = (jt == qt);
#pragma unroll
      for (int nb = 0; nb < 4; ++nb) {
        if (diag && nb > w) {
#pragma unroll
          for (int r = 0; r < 4; ++r)
            Pt[w][lq * 4 + r][nb * 16 + lm] = 0;
          continue;
        }
        f32x4 a = (f32x4){0.f, 0.f, 0.f, 0.f};
#pragma unroll
        for (int kc = 0; kc < 3; ++kc) {
          bf16x8 kf = *(const bf16x8*)&KV[cur][(kc * 4 + nb) * 512 + l * 8];
          a = __builtin_amdgcn_mfma_f32_16x16x32_bf16(qf[kc], kf, a, 0, 0, 0);
        }
#pragma unroll
        for (int r = 0; r < 4; ++r) {
          float s = a[r];
          if (diag && (nb * 16 + lm > w * 16 + lq * 4 + r)) s = -INFINITY;
          Pt[w][lq * 4 + r][nb * 16 + lm] = f2bf(__expf(s));
        }
      }

      bf16x8 pf0 = *(const bf16x8*)&Pt[w][lm][lq * 8];
      bf16x8 pf1 = *(const bf16x8*)&Pt[w][lm][32 + lq * 8];
#pragma unroll
      for (int db = 0; db < 6; ++db) {
        bf16x8 vf0 = *(const bf16x8*)&KV[cur][(12 + db * 2 + 0) * 512 + l * 8];
        bf16x8 vf1 = *(const bf16x8*)&KV[cur][(12 + db * 2 + 1) * 512 + l * 8];
        o[db] = __builtin_amdgcn_mfma_f32_16x16x32_bf16(pf0, vf0, o[db], 0, 0, 0);
        o[db] = __builtin_amdgcn_mfma_f32_16x16x32_bf16(pf1, vf1, o[db], 0, 0, 0);
      }
      o[6] = __builtin_amdgcn_mfma_f32_16x16x32_bf16(pf0, onef, o[6], 0, 0, 0);
      o[6] = __builtin_amdgcn_mfma_f32_16x16x32_bf16(pf1, onef, o[6], 0, 0, 0);
      cur ^= 1;
    }

#pragma unroll
    for (int r = 0; r < 4; ++r) {
      const float inv = 1.f / o[6][r];
      const size_t row = bT + q0 + w * 16 + lq * 4 + r;
#pragma unroll
      for (int db = 0; db < 6; ++db)
        y[row * C_ + h * D_ + db * 16 + lm] = f2bf(o[db][r] * inv);
    }
  }
}

// ---------------------------------------------------------------------------
extern "C" void kernel_launch(void* const* d_in, const int* in_sizes, int n_in,
                              void* d_out, int out_size, void* d_ws, size_t ws_size,
                              hipStream_t stream) {
  const float* x      = (const float*)d_in[0];
  const float* W_attn = (const float*)d_in[1];
  const float* b_attn = (const float*)d_in[2];
  const float* W_proj = (const float*)d_in[3];
  const float* b_proj = (const float*)d_in[4];
  float* out = (float*)d_out;

  // R16 workspace diet (80.2 -> 55.0 MB): qkv stride 1536 (V third never
  // written -- V goes to vt), yb aliases xb (xb dead after QKV; attn
  // writes yb strictly after QKV completes, same stream).
  char* ws = (char*)d_ws;
  unsigned short* xb  = (unsigned short*)(ws);                    // 12.58 MB
  unsigned short* WaT = (unsigned short*)(ws + 12582912);         //  3.54 MB
  unsigned short* WpT = (unsigned short*)(ws + 16121856);         //  1.18 MB
  unsigned short* qkv = (unsigned short*)(ws + 17301504);         // 25.17 MB
  unsigned short* vt  = (unsigned short*)(ws + 42467328);         // 12.58 MB
  unsigned short* yb  = xb;                                       // alias

  const float qscale = 0.10206207261596577f;  // 1/sqrt(96)

  // fused prep: x cast (6144 blocks) + both W transposes (2304 blocks)
  prep_kernel<<<6144 + 2304, 256, 0, stream>>>(x, xb, W_attn, WaT, W_proj, WpT);

  // qkv = x @ W_attn + b_attn: 128x128 tiles, 2-buffer 32KB, 1152 blocks
  gemm_mfma_kernel<false, true><<<(N1_ / 128) * (M_ / 128), 256, 0, stream>>>(
      xb, WaT, b_attn, qkv, vt, QS_, C_, qscale, 63, 6);
  // attn: 512 blocks, bh = id & 63 for XCD locality
  attn_mfma_kernel<<<8 * B_ * H_, 256, 0, stream>>>(qkv, vt, yb);
  // proj: 128x128 tiles, 64m x 6n = 384 blocks
  gemm_mfma_kernel<true, false><<<(C_ / 128) * (M_ / 128), 256, 0, stream>>>(
      yb, WpT, b_proj, out, nullptr, C_, 0, 1.f, 63, 6);
}